// Round 3
// baseline (267.267 us; speedup 1.0000x reference)
//
#include <hip/hip_runtime.h>

#define B_SZ  2
#define T_SEQ 2048
#define D_MOD 1024
#define NH    8
#define HD    128

typedef __attribute__((ext_vector_type(8))) short short8;   // 8 x bf16 frag
typedef __attribute__((ext_vector_type(4))) float f32x4;    // mfma accumulator

__device__ __forceinline__ short f2bf(float f) {
  unsigned u = __float_as_uint(f);
  unsigned r = u + 0x7fffu + ((u >> 16) & 1u);   // RNE
  return (short)(r >> 16);
}

__device__ __forceinline__ void gld_lds16(const short* g, short* l) {
  __builtin_amdgcn_global_load_lds(
      (const __attribute__((address_space(1))) void*)g,
      (__attribute__((address_space(3))) void*)l, 16, 0, 0);
}

// ---------------- decay table: dm[n] = mean_h exp(-theta_h*n) / sqrt(HD) ----
__global__ void decay_kernel(const float* __restrict__ theta,
                             float* __restrict__ dm) {
  int n = blockIdx.x * 256 + threadIdx.x;
  if (n >= T_SEQ) return;
  float nf = (float)n;
  float s = 0.f;
#pragma unroll
  for (int h = 0; h < NH; h++) s += __expf(-theta[h] * nf);
  dm[n] = s * (0.08838834764831845f / 8.0f);  // (1/sqrt(128)) * (1/H)
}

// ---------------- x fp32 -> bf16 (same layout) -----------------------------
__global__ __launch_bounds__(256) void cvt_x(const float* __restrict__ x,
                                             short* __restrict__ xb) {
  int i = (blockIdx.x * 256 + threadIdx.x) * 8;
  float4 a = *(const float4*)(x + i);
  float4 b = *(const float4*)(x + i + 4);
  short8 o;
  o[0] = f2bf(a.x); o[1] = f2bf(a.y); o[2] = f2bf(a.z); o[3] = f2bf(a.w);
  o[4] = f2bf(b.x); o[5] = f2bf(b.y); o[6] = f2bf(b.z); o[7] = f2bf(b.w);
  *(short8*)(xb + i) = o;
}

// ---------------- W (K,N) fp32 -> W^T (N,K) bf16, 32x32 LDS transpose ------
__global__ __launch_bounds__(256) void cvt_w(const float* __restrict__ Wq,
                                             const float* __restrict__ Wk,
                                             const float* __restrict__ Wv,
                                             const float* __restrict__ Wo,
                                             short* __restrict__ wt) {
  __shared__ float t[32][33];
  const int z = blockIdx.z;
  const float* __restrict__ W = (z == 0) ? Wq : (z == 1) ? Wk : (z == 2) ? Wv : Wo;
  short* __restrict__ dst = wt + (size_t)z * D_MOD * D_MOD;
  const int k0 = blockIdx.x * 32, n0 = blockIdx.y * 32;
  const int tx = threadIdx.x & 31, ty = threadIdx.x >> 5;
#pragma unroll
  for (int i = 0; i < 4; i++)
    t[ty * 4 + i][tx] = W[(size_t)(k0 + ty * 4 + i) * D_MOD + n0 + tx];
  __syncthreads();
#pragma unroll
  for (int i = 0; i < 4; i++)
    dst[(size_t)(n0 + ty * 4 + i) * D_MOD + k0 + tx] = f2bf(t[tx][ty * 4 + i]);
}

// ---------------- bf16 MFMA GEMM (m97 structure): QKV projections ----------
__global__ __launch_bounds__(256, 3) void gemm_qkv(
    const short* __restrict__ xb, const short* __restrict__ wt,
    short* __restrict__ qb, short* __restrict__ kb, short* __restrict__ vb) {
  __shared__ __align__(16) short As[128 * 32];   // [row][k] row-major, 8KB
  __shared__ __align__(16) short Bs[128 * 32];   // [col][k] (W^T rows), 8KB
  const int tid = threadIdx.x;
  const int l = tid & 63, w = tid >> 6;
  const int wr = w >> 1, wc = w & 1;
  const int row0 = blockIdx.x * 128;
  const int h = blockIdx.y;
  const int col0 = h * 128;
  const short* __restrict__ Wt = wt + (size_t)blockIdx.z * D_MOD * D_MOD;
  short* __restrict__ dst = (blockIdx.z == 0) ? qb : (blockIdx.z == 1) ? kb : vb;

  f32x4 acc[4][4];
#pragma unroll
  for (int m = 0; m < 4; m++)
#pragma unroll
    for (int n = 0; n < 4; n++) acc[m][n] = (f32x4){0.f, 0.f, 0.f, 0.f};

  const int cA = w * 2;
  const int sr = l >> 2;
  const int skq = (l & 3) << 3;

#pragma unroll
  for (int i = 0; i < 2; i++) {
    int c = cA + i;
    gld_lds16(xb + (size_t)(row0 + c * 16 + sr) * D_MOD + skq, As + c * 512);
    gld_lds16(Wt + (size_t)(col0 + c * 16 + sr) * D_MOD + skq, Bs + c * 512);
  }
  for (int ks = 0; ks < 32; ks++) {
    __syncthreads();
    short8 af[4], bf[4];
#pragma unroll
    for (int m = 0; m < 4; m++)
      af[m] = *(const short8*)&As[(wr * 64 + m * 16 + (l & 15)) * 32 + (l >> 4) * 8];
#pragma unroll
    for (int n = 0; n < 4; n++)
      bf[n] = *(const short8*)&Bs[(wc * 64 + n * 16 + (l & 15)) * 32 + (l >> 4) * 8];
#pragma unroll
    for (int m = 0; m < 4; m++)
#pragma unroll
      for (int n = 0; n < 4; n++)
        acc[m][n] =
            __builtin_amdgcn_mfma_f32_16x16x32_bf16(af[m], bf[n], acc[m][n], 0, 0, 0);
    __syncthreads();
    if (ks < 31) {
      const int k0 = (ks + 1) * 32;
#pragma unroll
      for (int i = 0; i < 2; i++) {
        int c = cA + i;
        gld_lds16(xb + (size_t)(row0 + c * 16 + sr) * D_MOD + k0 + skq, As + c * 512);
        gld_lds16(Wt + (size_t)(col0 + c * 16 + sr) * D_MOD + k0 + skq, Bs + c * 512);
      }
    }
  }
#pragma unroll
  for (int m = 0; m < 4; m++) {
#pragma unroll
    for (int j = 0; j < 4; j++) {
      int row = row0 + wr * 64 + m * 16 + (l >> 4) * 4 + j;
      int bb = row >> 11, t = row & (T_SEQ - 1);
      size_t base = ((size_t)(bb * NH + h) * T_SEQ + t) * HD + wc * 64 + (l & 15);
#pragma unroll
      for (int n = 0; n < 4; n++) dst[base + n * 16] = f2bf(acc[m][n][j]);
    }
  }
}

// ---------------- bf16 MFMA GEMM: output projection + bias (fp32 out) ------
__global__ __launch_bounds__(256, 3) void gemm_out(
    const short* __restrict__ yb, const short* __restrict__ wot,
    const float* __restrict__ bias, float* __restrict__ out) {
  __shared__ __align__(16) short As[128 * 32];
  __shared__ __align__(16) short Bs[128 * 32];
  const int tid = threadIdx.x;
  const int l = tid & 63, w = tid >> 6;
  const int wr = w >> 1, wc = w & 1;
  const int row0 = blockIdx.x * 128;
  const int col0 = blockIdx.y * 128;

  f32x4 acc[4][4];
#pragma unroll
  for (int m = 0; m < 4; m++)
#pragma unroll
    for (int n = 0; n < 4; n++) acc[m][n] = (f32x4){0.f, 0.f, 0.f, 0.f};

  const int cA = w * 2;
  const int sr = l >> 2;
  const int skq = (l & 3) << 3;

#pragma unroll
  for (int i = 0; i < 2; i++) {
    int c = cA + i;
    gld_lds16(yb + (size_t)(row0 + c * 16 + sr) * D_MOD + skq, As + c * 512);
    gld_lds16(wot + (size_t)(col0 + c * 16 + sr) * D_MOD + skq, Bs + c * 512);
  }
  for (int ks = 0; ks < 32; ks++) {
    __syncthreads();
    short8 af[4], bf[4];
#pragma unroll
    for (int m = 0; m < 4; m++)
      af[m] = *(const short8*)&As[(wr * 64 + m * 16 + (l & 15)) * 32 + (l >> 4) * 8];
#pragma unroll
    for (int n = 0; n < 4; n++)
      bf[n] = *(const short8*)&Bs[(wc * 64 + n * 16 + (l & 15)) * 32 + (l >> 4) * 8];
#pragma unroll
    for (int m = 0; m < 4; m++)
#pragma unroll
      for (int n = 0; n < 4; n++)
        acc[m][n] =
            __builtin_amdgcn_mfma_f32_16x16x32_bf16(af[m], bf[n], acc[m][n], 0, 0, 0);
    __syncthreads();
    if (ks < 31) {
      const int k0 = (ks + 1) * 32;
#pragma unroll
      for (int i = 0; i < 2; i++) {
        int c = cA + i;
        gld_lds16(yb + (size_t)(row0 + c * 16 + sr) * D_MOD + k0 + skq, As + c * 512);
        gld_lds16(wot + (size_t)(col0 + c * 16 + sr) * D_MOD + k0 + skq, Bs + c * 512);
      }
    }
  }
#pragma unroll
  for (int m = 0; m < 4; m++) {
#pragma unroll
    for (int j = 0; j < 4; j++) {
      int row = row0 + wr * 64 + m * 16 + (l >> 4) * 4 + j;
#pragma unroll
      for (int n = 0; n < 4; n++) {
        int col = col0 + wc * 64 + n * 16 + (l & 15);
        out[(size_t)row * D_MOD + col] = acc[m][n][j] + bias[col];
      }
    }
  }
}

// ---------------- flash retention, double-buffered K/V ---------------------
// grid = 512 blocks (qt 0..31, h 0..7, b 0..1), 256 threads = 4 waves.
// Per tile: prefetch K (global_load_lds direct) + V (regs) for tile jt+1,
// compute QK^T/softmax/PV on tile jt, repack V late, ONE barrier.
__global__ __launch_bounds__(256, 2) void attn_kernel(
    const short* __restrict__ qg, const short* __restrict__ kg,
    const short* __restrict__ vg, const float* __restrict__ dm_g,
    const float* __restrict__ gamma, const float* __restrict__ beta,
    short* __restrict__ yb) {
  __shared__ __align__(16) short KT[2][8192];   // 2 x 16KB [jb][kc][lane][8]
  __shared__ __align__(16) short VT[2][8192];   // 2 x 16KB [cb][kc2][lane][8]
  __shared__ __align__(16) float P2[4][1024];   // 16KB per-wave P roundtrip
  // total 80KB -> exactly 2 blocks/CU

  const int tid = threadIdx.x;
  const int l = tid & 63, w = tid >> 6;
  const int lm = l & 15, lq = l >> 4;

  int qt = blockIdx.x & 31;
  const int h = (blockIdx.x >> 5) & 7;
  const int b = blockIdx.x >> 8;
  if (b) qt = 31 - qt;  // complementary work pairing for co-resident blocks

  const size_t hoff = (size_t)(b * NH + h) * T_SEQ * HD;
  const short* __restrict__ Qh = qg + hoff;
  const short* __restrict__ Kh = kg + hoff;
  const short* __restrict__ Vh = vg + hoff;

  short8 qf[4];
  {
    int row = qt * 64 + w * 16 + lm;
#pragma unroll
    for (int kc = 0; kc < 4; kc++)
      qf[kc] = *(const short8*)(Qh + (size_t)row * HD + kc * 32 + lq * 8);
  }

  f32x4 zero4 = {0.f, 0.f, 0.f, 0.f};
  f32x4 o[8];
#pragma unroll
  for (int cb = 0; cb < 8; cb++) o[cb] = zero4;
  float m_r[4], l_r[4];
#pragma unroll
  for (int r = 0; r < 4; r++) { m_r[r] = -1e30f; l_r[r] = 0.f; }

  const int i_row0 = qt * 64 + w * 16 + lq * 4;
  const int njt = qt + 1;
  const int d0 = l * 2;

  unsigned vv[16];

  // ---- prologue: stage tile 0 into buffer 0
#pragma unroll
  for (int kc = 0; kc < 4; kc++)
    gld_lds16(Kh + (size_t)(w * 16 + lm) * HD + kc * 32 + lq * 8,
              &KT[0][(w * 4 + kc) * 512]);
#pragma unroll
  for (int p = 0; p < 2; p++)
#pragma unroll
    for (int jj = 0; jj < 8; jj++)
      vv[p * 8 + jj] =
          *(const unsigned*)(Vh + (size_t)((w + p * 4) * 8 + jj) * HD + d0);
#pragma unroll
  for (int p = 0; p < 2; p++) {
    const int jl = (w + p * 4) * 8;
    const int kc2 = jl >> 5, bq = (jl >> 3) & 3;
#pragma unroll
    for (int dd = 0; dd < 2; dd++) {
      const int d = d0 + dd;
      short8 col;
#pragma unroll
      for (int jj = 0; jj < 8; jj++) {
        unsigned u = vv[p * 8 + jj];
        col[jj] = (short)(dd ? (u >> 16) : (u & 0xffffu));
      }
      *(short8*)&VT[0][(((d >> 4) * 2 + kc2) * 64 + bq * 16 + (d & 15)) * 8] = col;
    }
  }
  __syncthreads();

  int cur = 0;
  for (int jt = 0; jt < njt; jt++) {
    const int j0 = jt * 64;
    const int nxt = cur ^ 1;
    const bool pf = (jt + 1) < njt;

    // ---- issue-early: prefetch tile jt+1 (K -> LDS direct, V -> regs)
    if (pf) {
      const int jn = j0 + 64;
#pragma unroll
      for (int kc = 0; kc < 4; kc++)
        gld_lds16(Kh + (size_t)(jn + w * 16 + lm) * HD + kc * 32 + lq * 8,
                  &KT[nxt][(w * 4 + kc) * 512]);
#pragma unroll
      for (int p = 0; p < 2; p++)
#pragma unroll
        for (int jj = 0; jj < 8; jj++)
          vv[p * 8 + jj] =
              *(const unsigned*)(Vh + (size_t)(jn + (w + p * 4) * 8 + jj) * HD + d0);
    }

    // ---- QK^T
    float s[4][4];
    __builtin_amdgcn_s_setprio(1);
#pragma unroll
    for (int jb = 0; jb < 4; jb++) {
      f32x4 acc = zero4;
#pragma unroll
      for (int kc = 0; kc < 4; kc++) {
        short8 kf = *(const short8*)&KT[cur][((jb * 4 + kc) * 64 + l) * 8];
        acc = __builtin_amdgcn_mfma_f32_16x16x32_bf16(qf[kc], kf, acc, 0, 0, 0);
      }
      const int j = j0 + jb * 16 + lm;
#pragma unroll
      for (int r = 0; r < 4; r++) {
        int delta = (i_row0 + r) - j;
        float dmv = dm_g[delta < 0 ? 0 : delta];
        s[jb][r] = (delta >= 0) ? acc[r] * dmv : -__builtin_inff();
      }
    }
    __builtin_amdgcn_s_setprio(0);

    // ---- online softmax
    float fac[4];
#pragma unroll
    for (int r = 0; r < 4; r++) {
      float mx = fmaxf(fmaxf(s[0][r], s[1][r]), fmaxf(s[2][r], s[3][r]));
      mx = fmaxf(mx, __shfl_xor(mx, 1));
      mx = fmaxf(mx, __shfl_xor(mx, 2));
      mx = fmaxf(mx, __shfl_xor(mx, 4));
      mx = fmaxf(mx, __shfl_xor(mx, 8));
      float mnew = fmaxf(m_r[r], mx);
      fac[r] = __expf(m_r[r] - mnew);
      m_r[r] = mnew;
    }
    float lsum[4] = {0.f, 0.f, 0.f, 0.f};
#pragma unroll
    for (int jb = 0; jb < 4; jb++) {
      const int jl2 = jb * 16 + lm;
      const int pbase = (jl2 >> 5) * 512 + ((jl2 & 31) >> 3) * 128 + (jl2 & 7);
#pragma unroll
      for (int r = 0; r < 4; r++) {
        float pv = __expf(s[jb][r] - m_r[r]);
        lsum[r] += pv;
        P2[w][pbase + (lq * 4 + r) * 8] = pv;
      }
    }
#pragma unroll
    for (int r = 0; r < 4; r++) {
      float sm = lsum[r];
      sm += __shfl_xor(sm, 1); sm += __shfl_xor(sm, 2);
      sm += __shfl_xor(sm, 4); sm += __shfl_xor(sm, 8);
      l_r[r] = l_r[r] * fac[r] + sm;
    }
#pragma unroll
    for (int cb = 0; cb < 8; cb++)
#pragma unroll
      for (int r = 0; r < 4; r++) o[cb][r] *= fac[r];

    // ---- PV
    __builtin_amdgcn_s_setprio(1);
#pragma unroll
    for (int kc2 = 0; kc2 < 2; kc2++) {
      f32x4 pa0 = *(const f32x4*)&P2[w][kc2 * 512 + l * 8];
      f32x4 pa1 = *(const f32x4*)&P2[w][kc2 * 512 + l * 8 + 4];
      short8 pb;
#pragma unroll
      for (int e = 0; e < 4; e++) {
        pb[e] = f2bf(pa0[e]);
        pb[e + 4] = f2bf(pa1[e]);
      }
#pragma unroll
      for (int cb = 0; cb < 8; cb++) {
        short8 vf = *(const short8*)&VT[cur][((cb * 2 + kc2) * 64 + l) * 8];
        o[cb] = __builtin_amdgcn_mfma_f32_16x16x32_bf16(pb, vf, o[cb], 0, 0, 0);
      }
    }
    __builtin_amdgcn_s_setprio(0);

    // ---- write-late: repack prefetched V into the other buffer
    if (pf) {
#pragma unroll
      for (int p = 0; p < 2; p++) {
        const int jl = (w + p * 4) * 8;
        const int kc2 = jl >> 5, bq = (jl >> 3) & 3;
#pragma unroll
        for (int dd = 0; dd < 2; dd++) {
          const int d = d0 + dd;
          short8 col;
#pragma unroll
          for (int jj = 0; jj < 8; jj++) {
            unsigned u = vv[p * 8 + jj];
            col[jj] = (short)(dd ? (u >> 16) : (u & 0xffffu));
          }
          *(short8*)&VT[nxt][(((d >> 4) * 2 + kc2) * 64 + bq * 16 + (d & 15)) * 8] =
              col;
        }
      }
    }
    __syncthreads();  // next tile fully staged; cur free for overwrite
    cur = nxt;
  }

  // ---- epilogue: 1/l, per-head GroupNorm, gamma/beta, write yb (bf16)
  float mu[4], rstd[4];
#pragma unroll
  for (int r = 0; r < 4; r++) {
    float inv = 1.0f / l_r[r];
    float sum = 0.f, sq = 0.f;
#pragma unroll
    for (int cb = 0; cb < 8; cb++) {
      float v2 = o[cb][r] * inv;
      o[cb][r] = v2;
      sum += v2;
      sq += v2 * v2;
    }
    sum += __shfl_xor(sum, 1); sum += __shfl_xor(sum, 2);
    sum += __shfl_xor(sum, 4); sum += __shfl_xor(sum, 8);
    sq += __shfl_xor(sq, 1); sq += __shfl_xor(sq, 2);
    sq += __shfl_xor(sq, 4); sq += __shfl_xor(sq, 8);
    float m2 = sum * (1.f / 128.f);
    mu[r] = m2;
    rstd[r] = rsqrtf(sq * (1.f / 128.f) - m2 * m2 + 1e-5f);
  }
  const int trow = qt * 64 + w * 16 + lq * 4;
#pragma unroll
  for (int cb = 0; cb < 8; cb++) {
    const int dcol = h * HD + cb * 16 + lm;
    const float g = gamma[dcol], be = beta[dcol];
#pragma unroll
    for (int r = 0; r < 4; r++) {
      float val = (o[cb][r] - mu[r]) * rstd[r] * g + be;
      yb[(size_t)(b * T_SEQ + trow + r) * D_MOD + dcol] = f2bf(val);
    }
  }
}

// ---------------------------------------------------------------------------
extern "C" void kernel_launch(void* const* d_in, const int* in_sizes, int n_in,
                              void* d_out, int out_size, void* d_ws,
                              size_t ws_size, hipStream_t stream) {
  const float* x     = (const float*)d_in[0];
  const float* Wq    = (const float*)d_in[1];
  const float* Wk    = (const float*)d_in[2];
  const float* Wv    = (const float*)d_in[3];
  const float* Wo    = (const float*)d_in[4];
  const float* bo    = (const float*)d_in[5];
  const float* theta = (const float*)d_in[6];
  const float* gamma = (const float*)d_in[7];
  const float* beta  = (const float*)d_in[8];
  float* out = (float*)d_out;

  char* ws = (char*)d_ws;
  const size_t MB = 1024 * 1024;
  short* qb = (short*)(ws + 0 * MB);    // 8 MB bf16 (B,H,T,HD)
  short* kb = (short*)(ws + 8 * MB);    // 8 MB
  short* vb = (short*)(ws + 16 * MB);   // 8 MB
  short* yb = (short*)(ws + 24 * MB);   // 8 MB bf16 (B*T, D)
  short* xb = (short*)(ws + 32 * MB);   // 8 MB bf16 (B*T, D)
  short* wt = (short*)(ws + 40 * MB);   // 8 MB: 4x (1024,1024) bf16 W^T
  float* dm = (float*)(ws + 48 * MB);   // 8 KB decay table

  decay_kernel<<<dim3(8), dim3(256), 0, stream>>>(theta, dm);
  cvt_x<<<dim3(2048), dim3(256), 0, stream>>>(x, xb);
  cvt_w<<<dim3(32, 32, 4), dim3(256), 0, stream>>>(Wq, Wk, Wv, Wo, wt);
  gemm_qkv<<<dim3(32, 8, 3), dim3(256), 0, stream>>>(xb, wt, qb, kb, vb);
  attn_kernel<<<dim3(512), dim3(256), 0, stream>>>(qb, kb, vb, dm, gamma, beta, yb);
  gemm_out<<<dim3(32, 8), dim3(256), 0, stream>>>(
      yb, wt + (size_t)3 * D_MOD * D_MOD, bo, out);
}

// Round 4
// 225.385 us; speedup vs baseline: 1.1858x; 1.1858x over previous
//
#include <hip/hip_runtime.h>

#define B_SZ  2
#define T_SEQ 2048
#define D_MOD 1024
#define NH    8
#define HD    128

typedef __attribute__((ext_vector_type(8))) short short8;   // 8 x bf16 frag
typedef __attribute__((ext_vector_type(4))) float f32x4;    // mfma accumulator

__device__ __forceinline__ short f2bf(float f) {
  unsigned u = __float_as_uint(f);
  unsigned r = u + 0x7fffu + ((u >> 16) & 1u);   // RNE
  return (short)(r >> 16);
}

__device__ __forceinline__ void gld_lds16(const short* g, short* l) {
  __builtin_amdgcn_global_load_lds(
      (const __attribute__((address_space(1))) void*)g,
      (__attribute__((address_space(3))) void*)l, 16, 0, 0);
}

// ---------------- decay table: dm[n] = mean_h exp(-theta_h*n) / sqrt(HD) ----
__global__ void decay_kernel(const float* __restrict__ theta,
                             float* __restrict__ dm) {
  int n = blockIdx.x * 256 + threadIdx.x;
  if (n >= T_SEQ) return;
  float nf = (float)n;
  float s = 0.f;
#pragma unroll
  for (int h = 0; h < NH; h++) s += __expf(-theta[h] * nf);
  dm[n] = s * (0.08838834764831845f / 8.0f);  // (1/sqrt(128)) * (1/H)
}

// ---------------- x fp32 -> bf16 (same layout) -----------------------------
__global__ __launch_bounds__(256) void cvt_x(const float* __restrict__ x,
                                             short* __restrict__ xb) {
  int i = (blockIdx.x * 256 + threadIdx.x) * 8;
  float4 a = *(const float4*)(x + i);
  float4 b = *(const float4*)(x + i + 4);
  short8 o;
  o[0] = f2bf(a.x); o[1] = f2bf(a.y); o[2] = f2bf(a.z); o[3] = f2bf(a.w);
  o[4] = f2bf(b.x); o[5] = f2bf(b.y); o[6] = f2bf(b.z); o[7] = f2bf(b.w);
  *(short8*)(xb + i) = o;
}

// ---------------- W (K,N) fp32 -> W^T (N,K) bf16, 32x32 LDS transpose ------
__global__ __launch_bounds__(256) void cvt_w(const float* __restrict__ Wq,
                                             const float* __restrict__ Wk,
                                             const float* __restrict__ Wv,
                                             const float* __restrict__ Wo,
                                             short* __restrict__ wt) {
  __shared__ float t[32][33];
  const int z = blockIdx.z;
  const float* __restrict__ W = (z == 0) ? Wq : (z == 1) ? Wk : (z == 2) ? Wv : Wo;
  short* __restrict__ dst = wt + (size_t)z * D_MOD * D_MOD;
  const int k0 = blockIdx.x * 32, n0 = blockIdx.y * 32;
  const int tx = threadIdx.x & 31, ty = threadIdx.x >> 5;
#pragma unroll
  for (int i = 0; i < 4; i++)
    t[ty * 4 + i][tx] = W[(size_t)(k0 + ty * 4 + i) * D_MOD + n0 + tx];
  __syncthreads();
#pragma unroll
  for (int i = 0; i < 4; i++)
    dst[(size_t)(n0 + ty * 4 + i) * D_MOD + k0 + tx] = f2bf(t[tx][ty * 4 + i]);
}

// ---------------- bf16 MFMA GEMM (m97 structure): QKV projections ----------
__global__ __launch_bounds__(256, 3) void gemm_qkv(
    const short* __restrict__ xb, const short* __restrict__ wt,
    short* __restrict__ qb, short* __restrict__ kb, short* __restrict__ vb) {
  __shared__ __align__(16) short As[128 * 32];   // [row][k] row-major, 8KB
  __shared__ __align__(16) short Bs[128 * 32];   // [col][k] (W^T rows), 8KB
  const int tid = threadIdx.x;
  const int l = tid & 63, w = tid >> 6;
  const int wr = w >> 1, wc = w & 1;
  const int row0 = blockIdx.x * 128;
  const int h = blockIdx.y;
  const int col0 = h * 128;
  const short* __restrict__ Wt = wt + (size_t)blockIdx.z * D_MOD * D_MOD;
  short* __restrict__ dst = (blockIdx.z == 0) ? qb : (blockIdx.z == 1) ? kb : vb;

  f32x4 acc[4][4];
#pragma unroll
  for (int m = 0; m < 4; m++)
#pragma unroll
    for (int n = 0; n < 4; n++) acc[m][n] = (f32x4){0.f, 0.f, 0.f, 0.f};

  const int cA = w * 2;
  const int sr = l >> 2;
  const int skq = (l & 3) << 3;

#pragma unroll
  for (int i = 0; i < 2; i++) {
    int c = cA + i;
    gld_lds16(xb + (size_t)(row0 + c * 16 + sr) * D_MOD + skq, As + c * 512);
    gld_lds16(Wt + (size_t)(col0 + c * 16 + sr) * D_MOD + skq, Bs + c * 512);
  }
  for (int ks = 0; ks < 32; ks++) {
    __syncthreads();
    short8 af[4], bf[4];
#pragma unroll
    for (int m = 0; m < 4; m++)
      af[m] = *(const short8*)&As[(wr * 64 + m * 16 + (l & 15)) * 32 + (l >> 4) * 8];
#pragma unroll
    for (int n = 0; n < 4; n++)
      bf[n] = *(const short8*)&Bs[(wc * 64 + n * 16 + (l & 15)) * 32 + (l >> 4) * 8];
#pragma unroll
    for (int m = 0; m < 4; m++)
#pragma unroll
      for (int n = 0; n < 4; n++)
        acc[m][n] =
            __builtin_amdgcn_mfma_f32_16x16x32_bf16(af[m], bf[n], acc[m][n], 0, 0, 0);
    __syncthreads();
    if (ks < 31) {
      const int k0 = (ks + 1) * 32;
#pragma unroll
      for (int i = 0; i < 2; i++) {
        int c = cA + i;
        gld_lds16(xb + (size_t)(row0 + c * 16 + sr) * D_MOD + k0 + skq, As + c * 512);
        gld_lds16(Wt + (size_t)(col0 + c * 16 + sr) * D_MOD + k0 + skq, Bs + c * 512);
      }
    }
  }
#pragma unroll
  for (int m = 0; m < 4; m++) {
#pragma unroll
    for (int j = 0; j < 4; j++) {
      int row = row0 + wr * 64 + m * 16 + (l >> 4) * 4 + j;
      int bb = row >> 11, t = row & (T_SEQ - 1);
      size_t base = ((size_t)(bb * NH + h) * T_SEQ + t) * HD + wc * 64 + (l & 15);
#pragma unroll
      for (int n = 0; n < 4; n++) dst[base + n * 16] = f2bf(acc[m][n][j]);
    }
  }
}

// ---------------- bf16 MFMA GEMM: output projection + bias (fp32 out) ------
__global__ __launch_bounds__(256, 3) void gemm_out(
    const short* __restrict__ yb, const short* __restrict__ wot,
    const float* __restrict__ bias, float* __restrict__ out) {
  __shared__ __align__(16) short As[128 * 32];
  __shared__ __align__(16) short Bs[128 * 32];
  const int tid = threadIdx.x;
  const int l = tid & 63, w = tid >> 6;
  const int wr = w >> 1, wc = w & 1;
  const int row0 = blockIdx.x * 128;
  const int col0 = blockIdx.y * 128;

  f32x4 acc[4][4];
#pragma unroll
  for (int m = 0; m < 4; m++)
#pragma unroll
    for (int n = 0; n < 4; n++) acc[m][n] = (f32x4){0.f, 0.f, 0.f, 0.f};

  const int cA = w * 2;
  const int sr = l >> 2;
  const int skq = (l & 3) << 3;

#pragma unroll
  for (int i = 0; i < 2; i++) {
    int c = cA + i;
    gld_lds16(yb + (size_t)(row0 + c * 16 + sr) * D_MOD + skq, As + c * 512);
    gld_lds16(wot + (size_t)(col0 + c * 16 + sr) * D_MOD + skq, Bs + c * 512);
  }
  for (int ks = 0; ks < 32; ks++) {
    __syncthreads();
    short8 af[4], bf[4];
#pragma unroll
    for (int m = 0; m < 4; m++)
      af[m] = *(const short8*)&As[(wr * 64 + m * 16 + (l & 15)) * 32 + (l >> 4) * 8];
#pragma unroll
    for (int n = 0; n < 4; n++)
      bf[n] = *(const short8*)&Bs[(wc * 64 + n * 16 + (l & 15)) * 32 + (l >> 4) * 8];
#pragma unroll
    for (int m = 0; m < 4; m++)
#pragma unroll
      for (int n = 0; n < 4; n++)
        acc[m][n] =
            __builtin_amdgcn_mfma_f32_16x16x32_bf16(af[m], bf[n], acc[m][n], 0, 0, 0);
    __syncthreads();
    if (ks < 31) {
      const int k0 = (ks + 1) * 32;
#pragma unroll
      for (int i = 0; i < 2; i++) {
        int c = cA + i;
        gld_lds16(yb + (size_t)(row0 + c * 16 + sr) * D_MOD + k0 + skq, As + c * 512);
        gld_lds16(wot + (size_t)(col0 + c * 16 + sr) * D_MOD + k0 + skq, Bs + c * 512);
      }
    }
  }
#pragma unroll
  for (int m = 0; m < 4; m++) {
#pragma unroll
    for (int j = 0; j < 4; j++) {
      int row = row0 + wr * 64 + m * 16 + (l >> 4) * 4 + j;
#pragma unroll
      for (int n = 0; n < 4; n++) {
        int col = col0 + wc * 64 + n * 16 + (l & 15);
        out[(size_t)row * D_MOD + col] = acc[m][n][j] + bias[col];
      }
    }
  }
}

// ---------------- flash retention, dbuf K/V, descending j, defer-rescale ---
// grid = 512 blocks (qt 0..31, h 0..7, b 0..1), 256 threads = 4 waves.
// j-tiles processed DESCENDING (diagonal first): decay mask makes the running
// max land in tile 0 -> rescale (shuffles + o-pass) skipped on later tiles.
// Tile body touches no VMEM results; prefetch drains only at tile-end barrier.
__global__ __launch_bounds__(256, 2) void attn_kernel(
    const short* __restrict__ qg, const short* __restrict__ kg,
    const short* __restrict__ vg, const float* __restrict__ dm_g,
    const float* __restrict__ gamma, const float* __restrict__ beta,
    short* __restrict__ yb) {
  __shared__ __align__(16) short KT[2][8192];   // 2 x 16KB [jb][kc][lane][8]
  __shared__ __align__(16) short VT[2][8192];   // 2 x 16KB [cb][kc2][lane][8]
  __shared__ __align__(16) short P2s[4][1024];  // 8KB per-wave P (bf16 packed)
  __shared__ float dm_s[T_SEQ];                 // 8KB decay table
  // total 80KB -> exactly 2 blocks/CU

  const int tid = threadIdx.x;
  const int l = tid & 63, w = tid >> 6;
  const int lm = l & 15, lq = l >> 4;

  int qt = blockIdx.x & 31;
  const int h = (blockIdx.x >> 5) & 7;
  const int b = blockIdx.x >> 8;
  if (b) qt = 31 - qt;  // complementary work pairing for co-resident blocks

  const size_t hoff = (size_t)(b * NH + h) * T_SEQ * HD;
  const short* __restrict__ Qh = qg + hoff;
  const short* __restrict__ Kh = kg + hoff;
  const short* __restrict__ Vh = vg + hoff;

  for (int i = tid * 4; i < T_SEQ; i += 1024)
    *(float4*)&dm_s[i] = *(const float4*)&dm_g[i];

  short8 qf[4];
  {
    int row = qt * 64 + w * 16 + lm;
#pragma unroll
    for (int kc = 0; kc < 4; kc++)
      qf[kc] = *(const short8*)(Qh + (size_t)row * HD + kc * 32 + lq * 8);
  }

  f32x4 zero4 = {0.f, 0.f, 0.f, 0.f};
  f32x4 o[8];
#pragma unroll
  for (int cb = 0; cb < 8; cb++) o[cb] = zero4;
  float m_r[4], l_r[4];
#pragma unroll
  for (int r = 0; r < 4; r++) { m_r[r] = -1e30f; l_r[r] = 0.f; }

  const int i_row0 = qt * 64 + w * 16 + lq * 4;
  const int d0 = l * 2;
  unsigned vv[16];

  // ---- prologue: stage tile t=qt into buffer 0
  {
    const int jP = qt * 64;
#pragma unroll
    for (int kc = 0; kc < 4; kc++)
      gld_lds16(Kh + (size_t)(jP + w * 16 + lm) * HD + kc * 32 + lq * 8,
                &KT[0][(w * 4 + kc) * 512]);
#pragma unroll
    for (int p = 0; p < 2; p++)
#pragma unroll
      for (int jj = 0; jj < 8; jj++)
        vv[p * 8 + jj] =
            *(const unsigned*)(Vh + (size_t)(jP + (w + p * 4) * 8 + jj) * HD + d0);
#pragma unroll
    for (int p = 0; p < 2; p++) {
      const int jl = (w + p * 4) * 8;
      const int kc2 = jl >> 5, bq = (jl >> 3) & 3;
#pragma unroll
      for (int dd = 0; dd < 2; dd++) {
        const int d = d0 + dd;
        short8 col;
#pragma unroll
        for (int jj = 0; jj < 8; jj++) {
          unsigned u = vv[p * 8 + jj];
          col[jj] = (short)(dd ? (u >> 16) : (u & 0xffffu));
        }
        *(short8*)&VT[0][(((d >> 4) * 2 + kc2) * 64 + bq * 16 + (d & 15)) * 8] = col;
      }
    }
  }
  __syncthreads();

  int cur = 0;
  for (int t = qt; t >= 0; --t) {
    const int j0 = t * 64;
    const int nxt = cur ^ 1;
    const bool pf = (t > 0);

    // ---- issue-early: prefetch tile t-1 (K -> LDS direct, V -> regs)
    if (pf) {
      const int jn = j0 - 64;
#pragma unroll
      for (int kc = 0; kc < 4; kc++)
        gld_lds16(Kh + (size_t)(jn + w * 16 + lm) * HD + kc * 32 + lq * 8,
                  &KT[nxt][(w * 4 + kc) * 512]);
#pragma unroll
      for (int p = 0; p < 2; p++)
#pragma unroll
        for (int jj = 0; jj < 8; jj++)
          vv[p * 8 + jj] =
              *(const unsigned*)(Vh + (size_t)(jn + (w + p * 4) * 8 + jj) * HD + d0);
    }

    // ---- QK^T
    float s[4][4];
    __builtin_amdgcn_s_setprio(1);
#pragma unroll
    for (int jb = 0; jb < 4; jb++) {
      f32x4 acc = zero4;
#pragma unroll
      for (int kc = 0; kc < 4; kc++) {
        short8 kf = *(const short8*)&KT[cur][((jb * 4 + kc) * 64 + l) * 8];
        acc = __builtin_amdgcn_mfma_f32_16x16x32_bf16(qf[kc], kf, acc, 0, 0, 0);
      }
      const int j = j0 + jb * 16 + lm;
#pragma unroll
      for (int r = 0; r < 4; r++) {
        int delta = (i_row0 + r) - j;
        float sv = acc[r] * dm_s[delta & (T_SEQ - 1)];
        s[jb][r] = (delta >= 0) ? sv : -__builtin_inff();
      }
    }
    __builtin_amdgcn_s_setprio(0);

    // ---- defer-rescale online softmax (THR=4)
    float smax[4];
#pragma unroll
    for (int r = 0; r < 4; r++)
      smax[r] = fmaxf(fmaxf(s[0][r], s[1][r]), fmaxf(s[2][r], s[3][r]));
    int grow = 0;
#pragma unroll
    for (int r = 0; r < 4; r++) grow |= (smax[r] > m_r[r] + 4.0f) ? 1 : 0;
    if (__any(grow)) {
#pragma unroll
      for (int r = 0; r < 4; r++) {
        float mx = smax[r];
        mx = fmaxf(mx, __shfl_xor(mx, 1));
        mx = fmaxf(mx, __shfl_xor(mx, 2));
        mx = fmaxf(mx, __shfl_xor(mx, 4));
        mx = fmaxf(mx, __shfl_xor(mx, 8));
        float mnew = fmaxf(m_r[r], mx);
        float fac = __expf(m_r[r] - mnew);
        m_r[r] = mnew;
        l_r[r] *= fac;
#pragma unroll
        for (int cb = 0; cb < 8; cb++) o[cb][r] *= fac;
      }
    }

    // ---- P = exp(s - m), store packed bf16 into A-frag layout
    float lsum[4] = {0.f, 0.f, 0.f, 0.f};
#pragma unroll
    for (int jb = 0; jb < 4; jb++) {
      const int jl2 = jb * 16 + lm;
      const int pbase = (jl2 >> 5) * 512 + ((jl2 & 31) >> 3) * 128 + (jl2 & 7);
#pragma unroll
      for (int r = 0; r < 4; r++) {
        float pv = __expf(s[jb][r] - m_r[r]);
        lsum[r] += pv;
        P2s[w][pbase + (lq * 4 + r) * 8] = f2bf(pv);
      }
    }
#pragma unroll
    for (int r = 0; r < 4; r++) {
      float sm = lsum[r];
      sm += __shfl_xor(sm, 1); sm += __shfl_xor(sm, 2);
      sm += __shfl_xor(sm, 4); sm += __shfl_xor(sm, 8);
      l_r[r] += sm;
    }

    // ---- PV
    __builtin_amdgcn_s_setprio(1);
#pragma unroll
    for (int kc2 = 0; kc2 < 2; kc2++) {
      short8 pb = *(const short8*)&P2s[w][kc2 * 512 + l * 8];
#pragma unroll
      for (int cb = 0; cb < 8; cb++) {
        short8 vf = *(const short8*)&VT[cur][((cb * 2 + kc2) * 64 + l) * 8];
        o[cb] = __builtin_amdgcn_mfma_f32_16x16x32_bf16(pb, vf, o[cb], 0, 0, 0);
      }
    }
    __builtin_amdgcn_s_setprio(0);

    // ---- write-late: repack prefetched V into the other buffer
    if (pf) {
#pragma unroll
      for (int p = 0; p < 2; p++) {
        const int jl = (w + p * 4) * 8;
        const int kc2 = jl >> 5, bq = (jl >> 3) & 3;
#pragma unroll
        for (int dd = 0; dd < 2; dd++) {
          const int d = d0 + dd;
          short8 col;
#pragma unroll
          for (int jj = 0; jj < 8; jj++) {
            unsigned u = vv[p * 8 + jj];
            col[jj] = (short)(dd ? (u >> 16) : (u & 0xffffu));
          }
          *(short8*)&VT[nxt][(((d >> 4) * 2 + kc2) * 64 + bq * 16 + (d & 15)) * 8] =
              col;
        }
      }
    }
    __syncthreads();  // next tile fully staged; cur free for overwrite
    cur = nxt;
  }

  // ---- epilogue: 1/l, per-head GroupNorm, gamma/beta, write yb (bf16)
  float mu[4], rstd[4];
#pragma unroll
  for (int r = 0; r < 4; r++) {
    float inv = 1.0f / l_r[r];
    float sum = 0.f, sq = 0.f;
#pragma unroll
    for (int cb = 0; cb < 8; cb++) {
      float v2 = o[cb][r] * inv;
      o[cb][r] = v2;
      sum += v2;
      sq += v2 * v2;
    }
    sum += __shfl_xor(sum, 1); sum += __shfl_xor(sum, 2);
    sum += __shfl_xor(sum, 4); sum += __shfl_xor(sum, 8);
    sq += __shfl_xor(sq, 1); sq += __shfl_xor(sq, 2);
    sq += __shfl_xor(sq, 4); sq += __shfl_xor(sq, 8);
    float m2 = sum * (1.f / 128.f);
    mu[r] = m2;
    rstd[r] = rsqrtf(sq * (1.f / 128.f) - m2 * m2 + 1e-5f);
  }
  const int trow = qt * 64 + w * 16 + lq * 4;
#pragma unroll
  for (int cb = 0; cb < 8; cb++) {
    const int dcol = h * HD + cb * 16 + lm;
    const float g = gamma[dcol], be = beta[dcol];
#pragma unroll
    for (int r = 0; r < 4; r++) {
      float val = (o[cb][r] - mu[r]) * rstd[r] * g + be;
      yb[(size_t)(b * T_SEQ + trow + r) * D_MOD + dcol] = f2bf(val);
    }
  }
}

// ---------------------------------------------------------------------------
extern "C" void kernel_launch(void* const* d_in, const int* in_sizes, int n_in,
                              void* d_out, int out_size, void* d_ws,
                              size_t ws_size, hipStream_t stream) {
  const float* x     = (const float*)d_in[0];
  const float* Wq    = (const float*)d_in[1];
  const float* Wk    = (const float*)d_in[2];
  const float* Wv    = (const float*)d_in[3];
  const float* Wo    = (const float*)d_in[4];
  const float* bo    = (const float*)d_in[5];
  const float* theta = (const float*)d_in[6];
  const float* gamma = (const float*)d_in[7];
  const float* beta  = (const float*)d_in[8];
  float* out = (float*)d_out;

  char* ws = (char*)d_ws;
  const size_t MB = 1024 * 1024;
  short* qb = (short*)(ws + 0 * MB);    // 8 MB bf16 (B,H,T,HD)
  short* kb = (short*)(ws + 8 * MB);    // 8 MB
  short* vb = (short*)(ws + 16 * MB);   // 8 MB
  short* yb = (short*)(ws + 24 * MB);   // 8 MB bf16 (B*T, D)
  short* xb = (short*)(ws + 32 * MB);   // 8 MB bf16 (B*T, D)
  short* wt = (short*)(ws + 40 * MB);   // 8 MB: 4x (1024,1024) bf16 W^T
  float* dm = (float*)(ws + 48 * MB);   // 8 KB decay table

  decay_kernel<<<dim3(8), dim3(256), 0, stream>>>(theta, dm);
  cvt_x<<<dim3(2048), dim3(256), 0, stream>>>(x, xb);
  cvt_w<<<dim3(32, 32, 4), dim3(256), 0, stream>>>(Wq, Wk, Wv, Wo, wt);
  gemm_qkv<<<dim3(32, 8, 3), dim3(256), 0, stream>>>(xb, wt, qb, kb, vb);
  attn_kernel<<<dim3(512), dim3(256), 0, stream>>>(qb, kb, vb, dm, gamma, beta, yb);
  gemm_out<<<dim3(32, 8), dim3(256), 0, stream>>>(
      yb, wt + (size_t)3 * D_MOD * D_MOD, bo, out);
}

// Round 6
// 219.350 us; speedup vs baseline: 1.2185x; 1.0275x over previous
//
#include <hip/hip_runtime.h>

#define B_SZ  2
#define T_SEQ 2048
#define D_MOD 1024
#define NH    8
#define HD    128

typedef __attribute__((ext_vector_type(8))) short short8;   // 8 x bf16 frag
typedef __attribute__((ext_vector_type(4))) float f32x4;    // mfma accumulator

__device__ __forceinline__ short f2bf(float f) {
  unsigned u = __float_as_uint(f);
  unsigned r = u + 0x7fffu + ((u >> 16) & 1u);   // RNE
  return (short)(r >> 16);
}

__device__ __forceinline__ void gld_lds16(const short* g, short* l) {
  __builtin_amdgcn_global_load_lds(
      (const __attribute__((address_space(1))) void*)g,
      (__attribute__((address_space(3))) void*)l, 16, 0, 0);
}

// ---------------- decay table: dm[n] = mean_h exp(-theta_h*n) / sqrt(HD) ----
__global__ void decay_kernel(const float* __restrict__ theta,
                             float* __restrict__ dm) {
  int n = blockIdx.x * 256 + threadIdx.x;
  if (n >= T_SEQ) return;
  float nf = (float)n;
  float s = 0.f;
#pragma unroll
  for (int h = 0; h < NH; h++) s += __expf(-theta[h] * nf);
  dm[n] = s * (0.08838834764831845f / 8.0f);  // (1/sqrt(128)) * (1/H)
}

// ---------------- x fp32 -> bf16 (same layout) -----------------------------
__global__ __launch_bounds__(256) void cvt_x(const float* __restrict__ x,
                                             short* __restrict__ xb) {
  int i = (blockIdx.x * 256 + threadIdx.x) * 8;
  float4 a = *(const float4*)(x + i);
  float4 b = *(const float4*)(x + i + 4);
  short8 o;
  o[0] = f2bf(a.x); o[1] = f2bf(a.y); o[2] = f2bf(a.z); o[3] = f2bf(a.w);
  o[4] = f2bf(b.x); o[5] = f2bf(b.y); o[6] = f2bf(b.z); o[7] = f2bf(b.w);
  *(short8*)(xb + i) = o;
}

// ---------------- W (K,N) fp32 -> W^T (N,K) bf16, 32x32 LDS transpose ------
__global__ __launch_bounds__(256) void cvt_w(const float* __restrict__ Wq,
                                             const float* __restrict__ Wk,
                                             const float* __restrict__ Wv,
                                             const float* __restrict__ Wo,
                                             short* __restrict__ wt) {
  __shared__ float t[32][33];
  const int z = blockIdx.z;
  const float* __restrict__ W = (z == 0) ? Wq : (z == 1) ? Wk : (z == 2) ? Wv : Wo;
  short* __restrict__ dst = wt + (size_t)z * D_MOD * D_MOD;
  const int k0 = blockIdx.x * 32, n0 = blockIdx.y * 32;
  const int tx = threadIdx.x & 31, ty = threadIdx.x >> 5;
#pragma unroll
  for (int i = 0; i < 4; i++)
    t[ty * 4 + i][tx] = W[(size_t)(k0 + ty * 4 + i) * D_MOD + n0 + tx];
  __syncthreads();
#pragma unroll
  for (int i = 0; i < 4; i++)
    dst[(size_t)(n0 + ty * 4 + i) * D_MOD + k0 + tx] = f2bf(t[tx][ty * 4 + i]);
}

// ---------------- bf16 MFMA GEMM (m97 structure): QKV projections ----------
__global__ __launch_bounds__(256, 3) void gemm_qkv(
    const short* __restrict__ xb, const short* __restrict__ wt,
    short* __restrict__ qb, short* __restrict__ kb, short* __restrict__ vb) {
  __shared__ __align__(16) short As[128 * 32];   // [row][k] row-major, 8KB
  __shared__ __align__(16) short Bs[128 * 32];   // [col][k] (W^T rows), 8KB
  const int tid = threadIdx.x;
  const int l = tid & 63, w = tid >> 6;
  const int wr = w >> 1, wc = w & 1;
  const int row0 = blockIdx.x * 128;
  const int h = blockIdx.y;
  const int col0 = h * 128;
  const short* __restrict__ Wt = wt + (size_t)blockIdx.z * D_MOD * D_MOD;
  short* __restrict__ dst = (blockIdx.z == 0) ? qb : (blockIdx.z == 1) ? kb : vb;

  f32x4 acc[4][4];
#pragma unroll
  for (int m = 0; m < 4; m++)
#pragma unroll
    for (int n = 0; n < 4; n++) acc[m][n] = (f32x4){0.f, 0.f, 0.f, 0.f};

  const int cA = w * 2;
  const int sr = l >> 2;
  const int skq = (l & 3) << 3;

#pragma unroll
  for (int i = 0; i < 2; i++) {
    int c = cA + i;
    gld_lds16(xb + (size_t)(row0 + c * 16 + sr) * D_MOD + skq, As + c * 512);
    gld_lds16(Wt + (size_t)(col0 + c * 16 + sr) * D_MOD + skq, Bs + c * 512);
  }
  for (int ks = 0; ks < 32; ks++) {
    __syncthreads();
    short8 af[4], bf[4];
#pragma unroll
    for (int m = 0; m < 4; m++)
      af[m] = *(const short8*)&As[(wr * 64 + m * 16 + (l & 15)) * 32 + (l >> 4) * 8];
#pragma unroll
    for (int n = 0; n < 4; n++)
      bf[n] = *(const short8*)&Bs[(wc * 64 + n * 16 + (l & 15)) * 32 + (l >> 4) * 8];
#pragma unroll
    for (int m = 0; m < 4; m++)
#pragma unroll
      for (int n = 0; n < 4; n++)
        acc[m][n] =
            __builtin_amdgcn_mfma_f32_16x16x32_bf16(af[m], bf[n], acc[m][n], 0, 0, 0);
    __syncthreads();
    if (ks < 31) {
      const int k0 = (ks + 1) * 32;
#pragma unroll
      for (int i = 0; i < 2; i++) {
        int c = cA + i;
        gld_lds16(xb + (size_t)(row0 + c * 16 + sr) * D_MOD + k0 + skq, As + c * 512);
        gld_lds16(Wt + (size_t)(col0 + c * 16 + sr) * D_MOD + k0 + skq, Bs + c * 512);
      }
    }
  }
#pragma unroll
  for (int m = 0; m < 4; m++) {
#pragma unroll
    for (int j = 0; j < 4; j++) {
      int row = row0 + wr * 64 + m * 16 + (l >> 4) * 4 + j;
      int bb = row >> 11, t = row & (T_SEQ - 1);
      size_t base = ((size_t)(bb * NH + h) * T_SEQ + t) * HD + wc * 64 + (l & 15);
#pragma unroll
      for (int n = 0; n < 4; n++) dst[base + n * 16] = f2bf(acc[m][n][j]);
    }
  }
}

// ---------------- bf16 MFMA GEMM: output projection + bias (fp32 out) ------
__global__ __launch_bounds__(256, 3) void gemm_out(
    const short* __restrict__ yb, const short* __restrict__ wot,
    const float* __restrict__ bias, float* __restrict__ out) {
  __shared__ __align__(16) short As[128 * 32];
  __shared__ __align__(16) short Bs[128 * 32];
  const int tid = threadIdx.x;
  const int l = tid & 63, w = tid >> 6;
  const int wr = w >> 1, wc = w & 1;
  const int row0 = blockIdx.x * 128;
  const int col0 = blockIdx.y * 128;

  f32x4 acc[4][4];
#pragma unroll
  for (int m = 0; m < 4; m++)
#pragma unroll
    for (int n = 0; n < 4; n++) acc[m][n] = (f32x4){0.f, 0.f, 0.f, 0.f};

  const int cA = w * 2;
  const int sr = l >> 2;
  const int skq = (l & 3) << 3;

#pragma unroll
  for (int i = 0; i < 2; i++) {
    int c = cA + i;
    gld_lds16(yb + (size_t)(row0 + c * 16 + sr) * D_MOD + skq, As + c * 512);
    gld_lds16(wot + (size_t)(col0 + c * 16 + sr) * D_MOD + skq, Bs + c * 512);
  }
  for (int ks = 0; ks < 32; ks++) {
    __syncthreads();
    short8 af[4], bf[4];
#pragma unroll
    for (int m = 0; m < 4; m++)
      af[m] = *(const short8*)&As[(wr * 64 + m * 16 + (l & 15)) * 32 + (l >> 4) * 8];
#pragma unroll
    for (int n = 0; n < 4; n++)
      bf[n] = *(const short8*)&Bs[(wc * 64 + n * 16 + (l & 15)) * 32 + (l >> 4) * 8];
#pragma unroll
    for (int m = 0; m < 4; m++)
#pragma unroll
      for (int n = 0; n < 4; n++)
        acc[m][n] =
            __builtin_amdgcn_mfma_f32_16x16x32_bf16(af[m], bf[n], acc[m][n], 0, 0, 0);
    __syncthreads();
    if (ks < 31) {
      const int k0 = (ks + 1) * 32;
#pragma unroll
      for (int i = 0; i < 2; i++) {
        int c = cA + i;
        gld_lds16(yb + (size_t)(row0 + c * 16 + sr) * D_MOD + k0 + skq, As + c * 512);
        gld_lds16(wot + (size_t)(col0 + c * 16 + sr) * D_MOD + k0 + skq, Bs + c * 512);
      }
    }
  }
#pragma unroll
  for (int m = 0; m < 4; m++) {
#pragma unroll
    for (int j = 0; j < 4; j++) {
      int row = row0 + wr * 64 + m * 16 + (l >> 4) * 4 + j;
#pragma unroll
      for (int n = 0; n < 4; n++) {
        int col = col0 + wc * 64 + n * 16 + (l & 15);
        out[(size_t)row * D_MOD + col] = acc[m][n][j] + bias[col];
      }
    }
  }
}

// ---------------- flash retention, swapped QK^T + in-register softmax ------
// grid = 512 blocks (XCD-swizzled), 256 threads = 4 waves, 16 q-rows/wave.
// S^T = mfma(K,Q): lane (lm,lq) holds 16 scores of q-row lm (k=jb*16+lq*4+r).
// Softmax fully in-register (in-lane tree + 2 shfl_xor); P redistributed to
// A-frags via cvt_pk + 16 shfl (no LDS round-trip). dbuf K/V, descending j,
// defer-rescale, write-late V repack, one barrier/tile.
__global__ __launch_bounds__(256, 2) void attn_kernel(
    const short* __restrict__ qg, const short* __restrict__ kg,
    const short* __restrict__ vg, const float* __restrict__ dm_g,
    const float* __restrict__ gamma, const float* __restrict__ beta,
    short* __restrict__ yb) {
  __shared__ __align__(16) short KT[2][8192];   // 2 x 16KB [jb][kc][lane][8]
  __shared__ __align__(16) short VT[2][8192];   // 2 x 16KB [cb][kc2][lane][8]
  __shared__ float dm_s[T_SEQ];                 // 8KB decay table
  // total 72KB -> 2 blocks/CU

  const int tid = threadIdx.x;
  const int l = tid & 63, w = tid >> 6;
  const int lm = l & 15, lq = l >> 4;

  // XCD-aware swizzle: 512 = 8 XCD x 64; logical chunk of 64 = 2 heads' full
  // qt range -> K/V working set ~4MB per XCD L2.
  const unsigned pbid = blockIdx.x;
  const unsigned lbid = (pbid & 7) * 64 + (pbid >> 3);
  const int qt = lbid & 31;
  const int h = (lbid >> 5) & 7;
  const int b = lbid >> 8;

  const size_t hoff = (size_t)(b * NH + h) * T_SEQ * HD;
  const short* __restrict__ Qh = qg + hoff;
  const short* __restrict__ Kh = kg + hoff;
  const short* __restrict__ Vh = vg + hoff;

  for (int i = tid * 4; i < T_SEQ; i += 1024)
    *(float4*)&dm_s[i] = *(const float4*)&dm_g[i];

  short8 qf[4];
  {
    int row = qt * 64 + w * 16 + lm;
#pragma unroll
    for (int kc = 0; kc < 4; kc++)
      qf[kc] = *(const short8*)(Qh + (size_t)row * HD + kc * 32 + lq * 8);
  }

  f32x4 zero4 = {0.f, 0.f, 0.f, 0.f};
  f32x4 o[8];
#pragma unroll
  for (int cb = 0; cb < 8; cb++) o[cb] = zero4;
  float m_r = -1e30f, l_r = 0.f;   // per-lane: q-row = lm of this wave

  const int i_row = qt * 64 + w * 16 + lm;   // softmax row owned by this lane
  const int d0 = l * 2;
  const int srcA = lm + 32 * (lq & 1);       // P-exchange source lanes
  const int srcB = srcA + 16;
  unsigned vv[16];

  // ---- prologue: stage tile t=qt into buffer 0
  {
    const int jP = qt * 64;
#pragma unroll
    for (int kc = 0; kc < 4; kc++)
      gld_lds16(Kh + (size_t)(jP + w * 16 + lm) * HD + kc * 32 + lq * 8,
                &KT[0][(w * 4 + kc) * 512]);
#pragma unroll
    for (int p = 0; p < 2; p++)
#pragma unroll
      for (int jj = 0; jj < 8; jj++)
        vv[p * 8 + jj] =
            *(const unsigned*)(Vh + (size_t)(jP + (w + p * 4) * 8 + jj) * HD + d0);
#pragma unroll
    for (int p = 0; p < 2; p++) {
      const int jl = (w + p * 4) * 8;
      const int kc2 = jl >> 5, bq = (jl >> 3) & 3;
#pragma unroll
      for (int dd = 0; dd < 2; dd++) {
        const int d = d0 + dd;
        short8 col;
#pragma unroll
        for (int jj = 0; jj < 8; jj++) {
          unsigned u = vv[p * 8 + jj];
          col[jj] = (short)(dd ? (u >> 16) : (u & 0xffffu));
        }
        *(short8*)&VT[0][(((d >> 4) * 2 + kc2) * 64 + bq * 16 + (d & 15)) * 8] = col;
      }
    }
  }
  __syncthreads();

  int cur = 0;
  for (int t = qt; t >= 0; --t) {
    const int j0 = t * 64;
    const int nxt = cur ^ 1;
    const bool pf = (t > 0);

    // ---- issue-early: prefetch tile t-1 (K -> LDS direct, V -> regs)
    if (pf) {
      const int jn = j0 - 64;
#pragma unroll
      for (int kc = 0; kc < 4; kc++)
        gld_lds16(Kh + (size_t)(jn + w * 16 + lm) * HD + kc * 32 + lq * 8,
                  &KT[nxt][(w * 4 + kc) * 512]);
#pragma unroll
      for (int p = 0; p < 2; p++)
#pragma unroll
        for (int jj = 0; jj < 8; jj++)
          vv[p * 8 + jj] =
              *(const unsigned*)(Vh + (size_t)(jn + (w + p * 4) * 8 + jj) * HD + d0);
    }

    // ---- swapped QK^T: S^T[k][q], lane holds k = jb*16 + lq*4 + r, q = lm
    float s[4][4];
    __builtin_amdgcn_s_setprio(1);
#pragma unroll
    for (int jb = 0; jb < 4; jb++) {
      f32x4 acc = zero4;
#pragma unroll
      for (int kc = 0; kc < 4; kc++) {
        short8 kf = *(const short8*)&KT[cur][((jb * 4 + kc) * 64 + l) * 8];
        acc = __builtin_amdgcn_mfma_f32_16x16x32_bf16(kf, qf[kc], acc, 0, 0, 0);
      }
#pragma unroll
      for (int r = 0; r < 4; r++) {
        int delta = i_row - (j0 + jb * 16 + lq * 4 + r);
        float sv = acc[r] * dm_s[delta & (T_SEQ - 1)];
        s[jb][r] = (delta >= 0) ? sv : -__builtin_inff();
      }
    }
    __builtin_amdgcn_s_setprio(0);

    // ---- defer-rescale online softmax, fully in-register
    float lmax = fmaxf(fmaxf(fmaxf(s[0][0], s[0][1]), fmaxf(s[0][2], s[0][3])),
                       fmaxf(fmaxf(s[1][0], s[1][1]), fmaxf(s[1][2], s[1][3])));
    lmax = fmaxf(lmax,
                 fmaxf(fmaxf(fmaxf(s[2][0], s[2][1]), fmaxf(s[2][2], s[2][3])),
                       fmaxf(fmaxf(s[3][0], s[3][1]), fmaxf(s[3][2], s[3][3]))));
    if (__any(lmax > m_r + 4.0f)) {
      float mx = lmax;
      mx = fmaxf(mx, __shfl_xor(mx, 16));
      mx = fmaxf(mx, __shfl_xor(mx, 32));
      float mnew = fmaxf(m_r, mx);
      float fac = __expf(m_r - mnew);
      m_r = mnew;
      l_r *= fac;
      float facr[4];
#pragma unroll
      for (int r = 0; r < 4; r++) facr[r] = __shfl(fac, lq * 4 + r);
#pragma unroll
      for (int cb = 0; cb < 8; cb++)
#pragma unroll
        for (int r = 0; r < 4; r++) o[cb][r] *= facr[r];
    }

    float lsum = 0.f;
#pragma unroll
    for (int jb = 0; jb < 4; jb++)
#pragma unroll
      for (int r = 0; r < 4; r++) {
        float pv = __expf(s[jb][r] - m_r);
        s[jb][r] = pv;
        lsum += pv;
      }
    lsum += __shfl_xor(lsum, 16);
    lsum += __shfl_xor(lsum, 32);
    l_r += lsum;

    // ---- pack P to bf16 pairs, redistribute to A-frag via shfl
    unsigned pw[4][2];
#pragma unroll
    for (int jb = 0; jb < 4; jb++) {
      asm("v_cvt_pk_bf16_f32 %0, %1, %2"
          : "=v"(pw[jb][0]) : "v"(s[jb][0]), "v"(s[jb][1]));
      asm("v_cvt_pk_bf16_f32 %0, %1, %2"
          : "=v"(pw[jb][1]) : "v"(s[jb][2]), "v"(s[jb][3]));
    }

    __builtin_amdgcn_s_setprio(1);
#pragma unroll
    for (int kc2 = 0; kc2 < 2; kc2++) {
      unsigned w0a = __shfl((int)pw[2 * kc2][0], srcA);
      unsigned w0b = __shfl((int)pw[2 * kc2 + 1][0], srcA);
      unsigned w1a = __shfl((int)pw[2 * kc2][1], srcA);
      unsigned w1b = __shfl((int)pw[2 * kc2 + 1][1], srcA);
      unsigned w2a = __shfl((int)pw[2 * kc2][0], srcB);
      unsigned w2b = __shfl((int)pw[2 * kc2 + 1][0], srcB);
      unsigned w3a = __shfl((int)pw[2 * kc2][1], srcB);
      unsigned w3b = __shfl((int)pw[2 * kc2 + 1][1], srcB);
      const bool hi = (lq & 2) != 0;
      unsigned w0 = hi ? w0b : w0a;
      unsigned w1 = hi ? w1b : w1a;
      unsigned w2 = hi ? w2b : w2a;
      unsigned w3 = hi ? w3b : w3a;
      short8 pb;
      pb[0] = (short)(w0 & 0xffffu); pb[1] = (short)(w0 >> 16);
      pb[2] = (short)(w1 & 0xffffu); pb[3] = (short)(w1 >> 16);
      pb[4] = (short)(w2 & 0xffffu); pb[5] = (short)(w2 >> 16);
      pb[6] = (short)(w3 & 0xffffu); pb[7] = (short)(w3 >> 16);
#pragma unroll
      for (int cb = 0; cb < 8; cb++) {
        short8 vf = *(const short8*)&VT[cur][((cb * 2 + kc2) * 64 + l) * 8];
        o[cb] = __builtin_amdgcn_mfma_f32_16x16x32_bf16(pb, vf, o[cb], 0, 0, 0);
      }
    }
    __builtin_amdgcn_s_setprio(0);

    // ---- write-late: repack prefetched V into the other buffer
    if (pf) {
#pragma unroll
      for (int p = 0; p < 2; p++) {
        const int jl = (w + p * 4) * 8;
        const int kc2 = jl >> 5, bq = (jl >> 3) & 3;
#pragma unroll
        for (int dd = 0; dd < 2; dd++) {
          const int d = d0 + dd;
          short8 col;
#pragma unroll
          for (int jj = 0; jj < 8; jj++) {
            unsigned u = vv[p * 8 + jj];
            col[jj] = (short)(dd ? (u >> 16) : (u & 0xffffu));
          }
          *(short8*)&VT[nxt][(((d >> 4) * 2 + kc2) * 64 + bq * 16 + (d & 15)) * 8] =
              col;
        }
      }
    }
    __syncthreads();  // next tile fully staged; cur free for overwrite
    cur = nxt;
  }

  // ---- epilogue: 1/l (via shfl from row-owner lanes), GroupNorm, write ----
  float linv[4];
#pragma unroll
  for (int r = 0; r < 4; r++) linv[r] = 1.0f / __shfl(l_r, lq * 4 + r);
  float mu[4], rstd[4];
#pragma unroll
  for (int r = 0; r < 4; r++) {
    float sum = 0.f, sq = 0.f;
#pragma unroll
    for (int cb = 0; cb < 8; cb++) {
      float v2 = o[cb][r] * linv[r];
      o[cb][r] = v2;
      sum += v2;
      sq += v2 * v2;
    }
    sum += __shfl_xor(sum, 1); sum += __shfl_xor(sum, 2);
    sum += __shfl_xor(sum, 4); sum += __shfl_xor(sum, 8);
    sq += __shfl_xor(sq, 1); sq += __shfl_xor(sq, 2);
    sq += __shfl_xor(sq, 4); sq += __shfl_xor(sq, 8);
    float m2 = sum * (1.f / 128.f);
    mu[r] = m2;
    rstd[r] = rsqrtf(sq * (1.f / 128.f) - m2 * m2 + 1e-5f);
  }
  const int trow = qt * 64 + w * 16 + lq * 4;
#pragma unroll
  for (int cb = 0; cb < 8; cb++) {
    const int dcol = h * HD + cb * 16 + lm;
    const float g = gamma[dcol], be = beta[dcol];
#pragma unroll
    for (int r = 0; r < 4; r++) {
      float val = (o[cb][r] - mu[r]) * rstd[r] * g + be;
      yb[(size_t)(b * T_SEQ + trow + r) * D_MOD + dcol] = f2bf(val);
    }
  }
}

// ---------------------------------------------------------------------------
extern "C" void kernel_launch(void* const* d_in, const int* in_sizes, int n_in,
                              void* d_out, int out_size, void* d_ws,
                              size_t ws_size, hipStream_t stream) {
  const float* x     = (const float*)d_in[0];
  const float* Wq    = (const float*)d_in[1];
  const float* Wk    = (const float*)d_in[2];
  const float* Wv    = (const float*)d_in[3];
  const float* Wo    = (const float*)d_in[4];
  const float* bo    = (const float*)d_in[5];
  const float* theta = (const float*)d_in[6];
  const float* gamma = (const float*)d_in[7];
  const float* beta  = (const float*)d_in[8];
  float* out = (float*)d_out;

  char* ws = (char*)d_ws;
  const size_t MB = 1024 * 1024;
  short* qb = (short*)(ws + 0 * MB);    // 8 MB bf16 (B,H,T,HD)
  short* kb = (short*)(ws + 8 * MB);    // 8 MB
  short* vb = (short*)(ws + 16 * MB);   // 8 MB
  short* yb = (short*)(ws + 24 * MB);   // 8 MB bf16 (B*T, D)
  short* xb = (short*)(ws + 32 * MB);   // 8 MB bf16 (B*T, D)
  short* wt = (short*)(ws + 40 * MB);   // 8 MB: 4x (1024,1024) bf16 W^T
  float* dm = (float*)(ws + 48 * MB);   // 8 KB decay table

  decay_kernel<<<dim3(8), dim3(256), 0, stream>>>(theta, dm);
  cvt_x<<<dim3(2048), dim3(256), 0, stream>>>(x, xb);
  cvt_w<<<dim3(32, 32, 4), dim3(256), 0, stream>>>(Wq, Wk, Wv, Wo, wt);
  gemm_qkv<<<dim3(32, 8, 3), dim3(256), 0, stream>>>(xb, wt, qb, kb, vb);
  attn_kernel<<<dim3(512), dim3(256), 0, stream>>>(qb, kb, vb, dm, gamma, beta, yb);
  gemm_out<<<dim3(32, 8), dim3(256), 0, stream>>>(
      yb, wt + (size_t)3 * D_MOD * D_MOD, bo, out);
}

// Round 7
// 218.561 us; speedup vs baseline: 1.2228x; 1.0036x over previous
//
#include <hip/hip_runtime.h>

#define B_SZ  2
#define T_SEQ 2048
#define D_MOD 1024
#define NH    8
#define HD    128

typedef __attribute__((ext_vector_type(8))) short short8;   // 8 x bf16 frag
typedef __attribute__((ext_vector_type(4))) float f32x4;    // mfma accumulator

__device__ __forceinline__ short f2bf(float f) {
  unsigned u = __float_as_uint(f);
  unsigned r = u + 0x7fffu + ((u >> 16) & 1u);   // RNE
  return (short)(r >> 16);
}

__device__ __forceinline__ void gld_lds16(const short* g, short* l) {
  __builtin_amdgcn_global_load_lds(
      (const __attribute__((address_space(1))) void*)g,
      (__attribute__((address_space(3))) void*)l, 16, 0, 0);
}

// ---------------- decay table: dm[n] = mean_h exp(-theta_h*n) / sqrt(HD) ----
__global__ void decay_kernel(const float* __restrict__ theta,
                             float* __restrict__ dm) {
  int n = blockIdx.x * 256 + threadIdx.x;
  if (n >= T_SEQ) return;
  float nf = (float)n;
  float s = 0.f;
#pragma unroll
  for (int h = 0; h < NH; h++) s += __expf(-theta[h] * nf);
  dm[n] = s * (0.08838834764831845f / 8.0f);  // (1/sqrt(128)) * (1/H)
}

// ---------------- x fp32 -> bf16 (same layout) -----------------------------
__global__ __launch_bounds__(256) void cvt_x(const float* __restrict__ x,
                                             short* __restrict__ xb) {
  int i = (blockIdx.x * 256 + threadIdx.x) * 8;
  float4 a = *(const float4*)(x + i);
  float4 b = *(const float4*)(x + i + 4);
  short8 o;
  o[0] = f2bf(a.x); o[1] = f2bf(a.y); o[2] = f2bf(a.z); o[3] = f2bf(a.w);
  o[4] = f2bf(b.x); o[5] = f2bf(b.y); o[6] = f2bf(b.z); o[7] = f2bf(b.w);
  *(short8*)(xb + i) = o;
}

// ---------------- W (K,N) fp32 -> W^T (N,K) bf16, 32x32 LDS transpose ------
__global__ __launch_bounds__(256) void cvt_w(const float* __restrict__ Wq,
                                             const float* __restrict__ Wk,
                                             const float* __restrict__ Wv,
                                             const float* __restrict__ Wo,
                                             short* __restrict__ wt) {
  __shared__ float t[32][33];
  const int z = blockIdx.z;
  const float* __restrict__ W = (z == 0) ? Wq : (z == 1) ? Wk : (z == 2) ? Wv : Wo;
  short* __restrict__ dst = wt + (size_t)z * D_MOD * D_MOD;
  const int k0 = blockIdx.x * 32, n0 = blockIdx.y * 32;
  const int tx = threadIdx.x & 31, ty = threadIdx.x >> 5;
#pragma unroll
  for (int i = 0; i < 4; i++)
    t[ty * 4 + i][tx] = W[(size_t)(k0 + ty * 4 + i) * D_MOD + n0 + tx];
  __syncthreads();
#pragma unroll
  for (int i = 0; i < 4; i++)
    dst[(size_t)(n0 + ty * 4 + i) * D_MOD + k0 + tx] = f2bf(t[tx][ty * 4 + i]);
}

// ---------------- bf16 MFMA GEMM (m97 structure): QKV projections ----------
__global__ __launch_bounds__(256, 3) void gemm_qkv(
    const short* __restrict__ xb, const short* __restrict__ wt,
    short* __restrict__ qb, short* __restrict__ kb, short* __restrict__ vb) {
  __shared__ __align__(16) short As[128 * 32];   // [row][k] row-major, 8KB
  __shared__ __align__(16) short Bs[128 * 32];   // [col][k] (W^T rows), 8KB
  const int tid = threadIdx.x;
  const int l = tid & 63, w = tid >> 6;
  const int wr = w >> 1, wc = w & 1;
  const int row0 = blockIdx.x * 128;
  const int h = blockIdx.y;
  const int col0 = h * 128;
  const short* __restrict__ Wt = wt + (size_t)blockIdx.z * D_MOD * D_MOD;
  short* __restrict__ dst = (blockIdx.z == 0) ? qb : (blockIdx.z == 1) ? kb : vb;

  f32x4 acc[4][4];
#pragma unroll
  for (int m = 0; m < 4; m++)
#pragma unroll
    for (int n = 0; n < 4; n++) acc[m][n] = (f32x4){0.f, 0.f, 0.f, 0.f};

  const int cA = w * 2;
  const int sr = l >> 2;
  const int skq = (l & 3) << 3;

#pragma unroll
  for (int i = 0; i < 2; i++) {
    int c = cA + i;
    gld_lds16(xb + (size_t)(row0 + c * 16 + sr) * D_MOD + skq, As + c * 512);
    gld_lds16(Wt + (size_t)(col0 + c * 16 + sr) * D_MOD + skq, Bs + c * 512);
  }
  for (int ks = 0; ks < 32; ks++) {
    __syncthreads();
    short8 af[4], bf[4];
#pragma unroll
    for (int m = 0; m < 4; m++)
      af[m] = *(const short8*)&As[(wr * 64 + m * 16 + (l & 15)) * 32 + (l >> 4) * 8];
#pragma unroll
    for (int n = 0; n < 4; n++)
      bf[n] = *(const short8*)&Bs[(wc * 64 + n * 16 + (l & 15)) * 32 + (l >> 4) * 8];
#pragma unroll
    for (int m = 0; m < 4; m++)
#pragma unroll
      for (int n = 0; n < 4; n++)
        acc[m][n] =
            __builtin_amdgcn_mfma_f32_16x16x32_bf16(af[m], bf[n], acc[m][n], 0, 0, 0);
    __syncthreads();
    if (ks < 31) {
      const int k0 = (ks + 1) * 32;
#pragma unroll
      for (int i = 0; i < 2; i++) {
        int c = cA + i;
        gld_lds16(xb + (size_t)(row0 + c * 16 + sr) * D_MOD + k0 + skq, As + c * 512);
        gld_lds16(Wt + (size_t)(col0 + c * 16 + sr) * D_MOD + k0 + skq, Bs + c * 512);
      }
    }
  }
#pragma unroll
  for (int m = 0; m < 4; m++) {
#pragma unroll
    for (int j = 0; j < 4; j++) {
      int row = row0 + wr * 64 + m * 16 + (l >> 4) * 4 + j;
      int bb = row >> 11, t = row & (T_SEQ - 1);
      size_t base = ((size_t)(bb * NH + h) * T_SEQ + t) * HD + wc * 64 + (l & 15);
#pragma unroll
      for (int n = 0; n < 4; n++) dst[base + n * 16] = f2bf(acc[m][n][j]);
    }
  }
}

// ---------------- bf16 MFMA GEMM: output projection + bias (fp32 out) ------
__global__ __launch_bounds__(256, 3) void gemm_out(
    const short* __restrict__ yb, const short* __restrict__ wot,
    const float* __restrict__ bias, float* __restrict__ out) {
  __shared__ __align__(16) short As[128 * 32];
  __shared__ __align__(16) short Bs[128 * 32];
  const int tid = threadIdx.x;
  const int l = tid & 63, w = tid >> 6;
  const int wr = w >> 1, wc = w & 1;
  const int row0 = blockIdx.x * 128;
  const int col0 = blockIdx.y * 128;

  f32x4 acc[4][4];
#pragma unroll
  for (int m = 0; m < 4; m++)
#pragma unroll
    for (int n = 0; n < 4; n++) acc[m][n] = (f32x4){0.f, 0.f, 0.f, 0.f};

  const int cA = w * 2;
  const int sr = l >> 2;
  const int skq = (l & 3) << 3;

#pragma unroll
  for (int i = 0; i < 2; i++) {
    int c = cA + i;
    gld_lds16(yb + (size_t)(row0 + c * 16 + sr) * D_MOD + skq, As + c * 512);
    gld_lds16(wot + (size_t)(col0 + c * 16 + sr) * D_MOD + skq, Bs + c * 512);
  }
  for (int ks = 0; ks < 32; ks++) {
    __syncthreads();
    short8 af[4], bf[4];
#pragma unroll
    for (int m = 0; m < 4; m++)
      af[m] = *(const short8*)&As[(wr * 64 + m * 16 + (l & 15)) * 32 + (l >> 4) * 8];
#pragma unroll
    for (int n = 0; n < 4; n++)
      bf[n] = *(const short8*)&Bs[(wc * 64 + n * 16 + (l & 15)) * 32 + (l >> 4) * 8];
#pragma unroll
    for (int m = 0; m < 4; m++)
#pragma unroll
      for (int n = 0; n < 4; n++)
        acc[m][n] =
            __builtin_amdgcn_mfma_f32_16x16x32_bf16(af[m], bf[n], acc[m][n], 0, 0, 0);
    __syncthreads();
    if (ks < 31) {
      const int k0 = (ks + 1) * 32;
#pragma unroll
      for (int i = 0; i < 2; i++) {
        int c = cA + i;
        gld_lds16(yb + (size_t)(row0 + c * 16 + sr) * D_MOD + k0 + skq, As + c * 512);
        gld_lds16(wot + (size_t)(col0 + c * 16 + sr) * D_MOD + k0 + skq, Bs + c * 512);
      }
    }
  }
#pragma unroll
  for (int m = 0; m < 4; m++) {
#pragma unroll
    for (int j = 0; j < 4; j++) {
      int row = row0 + wr * 64 + m * 16 + (l >> 4) * 4 + j;
#pragma unroll
      for (int n = 0; n < 4; n++) {
        int col = col0 + wc * 64 + n * 16 + (l & 15);
        out[(size_t)row * D_MOD + col] = acc[m][n][j] + bias[col];
      }
    }
  }
}

// ---------------- flash retention, register-blocked tile body --------------
// grid = 512 blocks (XCD-swizzled), 256 threads = 4 waves, 16 q-rows/wave.
// Tile body ILP-forced: all 16 K frags ds_read -> regs before QK^T; all 16
// V frags ds_read -> regs right after QK^T (latency hides under softmax).
// Swapped QK^T, in-register softmax, dbuf K/V, descending j, defer-rescale.
__global__ __launch_bounds__(256, 2) void attn_kernel(
    const short* __restrict__ qg, const short* __restrict__ kg,
    const short* __restrict__ vg, const float* __restrict__ dm_g,
    const float* __restrict__ gamma, const float* __restrict__ beta,
    short* __restrict__ yb) {
  __shared__ __align__(16) short KT[2][8192];   // 2 x 16KB [jb][kc][lane][8]
  __shared__ __align__(16) short VT[2][8192];   // 2 x 16KB [cb][kc2][lane][8]
  __shared__ float dm_s[T_SEQ];                 // 8KB decay table
  // total 72KB -> 2 blocks/CU

  const int tid = threadIdx.x;
  const int l = tid & 63, w = tid >> 6;
  const int lm = l & 15, lq = l >> 4;

  const unsigned pbid = blockIdx.x;
  const unsigned lbid = (pbid & 7) * 64 + (pbid >> 3);
  const int qt = lbid & 31;
  const int h = (lbid >> 5) & 7;
  const int b = lbid >> 8;

  const size_t hoff = (size_t)(b * NH + h) * T_SEQ * HD;
  const short* __restrict__ Qh = qg + hoff;
  const short* __restrict__ Kh = kg + hoff;
  const short* __restrict__ Vh = vg + hoff;

  for (int i = tid * 4; i < T_SEQ; i += 1024)
    *(float4*)&dm_s[i] = *(const float4*)&dm_g[i];

  short8 qf[4];
  {
    int row = qt * 64 + w * 16 + lm;
#pragma unroll
    for (int kc = 0; kc < 4; kc++)
      qf[kc] = *(const short8*)(Qh + (size_t)row * HD + kc * 32 + lq * 8);
  }

  f32x4 zero4 = {0.f, 0.f, 0.f, 0.f};
  f32x4 o[8];
#pragma unroll
  for (int cb = 0; cb < 8; cb++) o[cb] = zero4;
  float m_r = -1e30f, l_r = 0.f;   // per-lane: q-row = lm of this wave

  const int i_row = qt * 64 + w * 16 + lm;   // softmax row owned by this lane
  const int d0 = l * 2;
  const int srcA = lm + 32 * (lq & 1);       // P-exchange source lanes
  const int srcB = srcA + 16;
  unsigned vv[16];

  // ---- prologue: stage tile t=qt into buffer 0
  {
    const int jP = qt * 64;
#pragma unroll
    for (int kc = 0; kc < 4; kc++)
      gld_lds16(Kh + (size_t)(jP + w * 16 + lm) * HD + kc * 32 + lq * 8,
                &KT[0][(w * 4 + kc) * 512]);
#pragma unroll
    for (int p = 0; p < 2; p++)
#pragma unroll
      for (int jj = 0; jj < 8; jj++)
        vv[p * 8 + jj] =
            *(const unsigned*)(Vh + (size_t)(jP + (w + p * 4) * 8 + jj) * HD + d0);
#pragma unroll
    for (int p = 0; p < 2; p++) {
      const int jl = (w + p * 4) * 8;
      const int kc2 = jl >> 5, bq = (jl >> 3) & 3;
#pragma unroll
      for (int dd = 0; dd < 2; dd++) {
        const int d = d0 + dd;
        short8 col;
#pragma unroll
        for (int jj = 0; jj < 8; jj++) {
          unsigned u = vv[p * 8 + jj];
          col[jj] = (short)(dd ? (u >> 16) : (u & 0xffffu));
        }
        *(short8*)&VT[0][(((d >> 4) * 2 + kc2) * 64 + bq * 16 + (d & 15)) * 8] = col;
      }
    }
  }
  __syncthreads();

  int cur = 0;
  for (int t = qt; t >= 0; --t) {
    const int j0 = t * 64;
    const int nxt = cur ^ 1;
    const bool pf = (t > 0);

    // ---- issue-early: prefetch tile t-1 (K -> LDS direct, V -> regs)
    if (pf) {
      const int jn = j0 - 64;
#pragma unroll
      for (int kc = 0; kc < 4; kc++)
        gld_lds16(Kh + (size_t)(jn + w * 16 + lm) * HD + kc * 32 + lq * 8,
                  &KT[nxt][(w * 4 + kc) * 512]);
#pragma unroll
      for (int p = 0; p < 2; p++)
#pragma unroll
        for (int jj = 0; jj < 8; jj++)
          vv[p * 8 + jj] =
              *(const unsigned*)(Vh + (size_t)(jn + (w + p * 4) * 8 + jj) * HD + d0);
    }

    // ---- register-block: ALL 16 K frags first (pipelined ds_read_b128)
    short8 kfr[16];
#pragma unroll
    for (int jb = 0; jb < 4; jb++)
#pragma unroll
      for (int kc = 0; kc < 4; kc++)
        kfr[jb * 4 + kc] = *(const short8*)&KT[cur][((jb * 4 + kc) * 64 + l) * 8];

    // ---- swapped QK^T: S^T[k][q], lane holds k = jb*16 + lq*4 + r, q = lm
    float s[4][4];
    __builtin_amdgcn_s_setprio(1);
#pragma unroll
    for (int jb = 0; jb < 4; jb++) {
      f32x4 acc = zero4;
#pragma unroll
      for (int kc = 0; kc < 4; kc++)
        acc = __builtin_amdgcn_mfma_f32_16x16x32_bf16(kfr[jb * 4 + kc], qf[kc],
                                                      acc, 0, 0, 0);
#pragma unroll
      for (int r = 0; r < 4; r++) {
        int delta = i_row - (j0 + jb * 16 + lq * 4 + r);
        float sv = acc[r] * dm_s[delta & (T_SEQ - 1)];
        s[jb][r] = (delta >= 0) ? sv : -__builtin_inff();
      }
    }
    __builtin_amdgcn_s_setprio(0);

    // ---- issue ALL 16 V frag reads now; latency hides under softmax
    short8 vfr[16];
#pragma unroll
    for (int cb = 0; cb < 8; cb++)
#pragma unroll
      for (int kc2 = 0; kc2 < 2; kc2++)
        vfr[cb * 2 + kc2] =
            *(const short8*)&VT[cur][((cb * 2 + kc2) * 64 + l) * 8];

    // ---- defer-rescale online softmax, fully in-register
    float lmax = fmaxf(fmaxf(fmaxf(s[0][0], s[0][1]), fmaxf(s[0][2], s[0][3])),
                       fmaxf(fmaxf(s[1][0], s[1][1]), fmaxf(s[1][2], s[1][3])));
    lmax = fmaxf(lmax,
                 fmaxf(fmaxf(fmaxf(s[2][0], s[2][1]), fmaxf(s[2][2], s[2][3])),
                       fmaxf(fmaxf(s[3][0], s[3][1]), fmaxf(s[3][2], s[3][3]))));
    if (__any(lmax > m_r + 4.0f)) {
      float mx = lmax;
      mx = fmaxf(mx, __shfl_xor(mx, 16));
      mx = fmaxf(mx, __shfl_xor(mx, 32));
      float mnew = fmaxf(m_r, mx);
      float fac = __expf(m_r - mnew);
      m_r = mnew;
      l_r *= fac;
      float facr[4];
#pragma unroll
      for (int r = 0; r < 4; r++) facr[r] = __shfl(fac, lq * 4 + r);
#pragma unroll
      for (int cb = 0; cb < 8; cb++)
#pragma unroll
        for (int r = 0; r < 4; r++) o[cb][r] *= facr[r];
    }

    float lsum = 0.f;
#pragma unroll
    for (int jb = 0; jb < 4; jb++)
#pragma unroll
      for (int r = 0; r < 4; r++) {
        float pv = __expf(s[jb][r] - m_r);
        s[jb][r] = pv;
        lsum += pv;
      }
    lsum += __shfl_xor(lsum, 16);
    lsum += __shfl_xor(lsum, 32);
    l_r += lsum;

    // ---- pack P to bf16 pairs, redistribute to A-frag via shfl
    unsigned pw[4][2];
#pragma unroll
    for (int jb = 0; jb < 4; jb++) {
      asm("v_cvt_pk_bf16_f32 %0, %1, %2"
          : "=v"(pw[jb][0]) : "v"(s[jb][0]), "v"(s[jb][1]));
      asm("v_cvt_pk_bf16_f32 %0, %1, %2"
          : "=v"(pw[jb][1]) : "v"(s[jb][2]), "v"(s[jb][3]));
    }

    __builtin_amdgcn_s_setprio(1);
#pragma unroll
    for (int kc2 = 0; kc2 < 2; kc2++) {
      unsigned w0a = __shfl((int)pw[2 * kc2][0], srcA);
      unsigned w0b = __shfl((int)pw[2 * kc2 + 1][0], srcA);
      unsigned w1a = __shfl((int)pw[2 * kc2][1], srcA);
      unsigned w1b = __shfl((int)pw[2 * kc2 + 1][1], srcA);
      unsigned w2a = __shfl((int)pw[2 * kc2][0], srcB);
      unsigned w2b = __shfl((int)pw[2 * kc2 + 1][0], srcB);
      unsigned w3a = __shfl((int)pw[2 * kc2][1], srcB);
      unsigned w3b = __shfl((int)pw[2 * kc2 + 1][1], srcB);
      const bool hi = (lq & 2) != 0;
      unsigned w0 = hi ? w0b : w0a;
      unsigned w1 = hi ? w1b : w1a;
      unsigned w2 = hi ? w2b : w2a;
      unsigned w3 = hi ? w3b : w3a;
      short8 pb;
      pb[0] = (short)(w0 & 0xffffu); pb[1] = (short)(w0 >> 16);
      pb[2] = (short)(w1 & 0xffffu); pb[3] = (short)(w1 >> 16);
      pb[4] = (short)(w2 & 0xffffu); pb[5] = (short)(w2 >> 16);
      pb[6] = (short)(w3 & 0xffffu); pb[7] = (short)(w3 >> 16);
#pragma unroll
      for (int cb = 0; cb < 8; cb++)
        o[cb] = __builtin_amdgcn_mfma_f32_16x16x32_bf16(pb, vfr[cb * 2 + kc2],
                                                        o[cb], 0, 0, 0);
    }
    __builtin_amdgcn_s_setprio(0);

    // ---- write-late: repack prefetched V into the other buffer
    if (pf) {
#pragma unroll
      for (int p = 0; p < 2; p++) {
        const int jl = (w + p * 4) * 8;
        const int kc2 = jl >> 5, bq = (jl >> 3) & 3;
#pragma unroll
        for (int dd = 0; dd < 2; dd++) {
          const int d = d0 + dd;
          short8 col;
#pragma unroll
          for (int jj = 0; jj < 8; jj++) {
            unsigned u = vv[p * 8 + jj];
            col[jj] = (short)(dd ? (u >> 16) : (u & 0xffffu));
          }
          *(short8*)&VT[nxt][(((d >> 4) * 2 + kc2) * 64 + bq * 16 + (d & 15)) * 8] =
              col;
        }
      }
    }
    __syncthreads();  // next tile fully staged; cur free for overwrite
    cur = nxt;
  }

  // ---- epilogue: 1/l (via shfl from row-owner lanes), GroupNorm, write ----
  float linv[4];
#pragma unroll
  for (int r = 0; r < 4; r++) linv[r] = 1.0f / __shfl(l_r, lq * 4 + r);
  float mu[4], rstd[4];
#pragma unroll
  for (int r = 0; r < 4; r++) {
    float sum = 0.f, sq = 0.f;
#pragma unroll
    for (int cb = 0; cb < 8; cb++) {
      float v2 = o[cb][r] * linv[r];
      o[cb][r] = v2;
      sum += v2;
      sq += v2 * v2;
    }
    sum += __shfl_xor(sum, 1); sum += __shfl_xor(sum, 2);
    sum += __shfl_xor(sum, 4); sum += __shfl_xor(sum, 8);
    sq += __shfl_xor(sq, 1); sq += __shfl_xor(sq, 2);
    sq += __shfl_xor(sq, 4); sq += __shfl_xor(sq, 8);
    float m2 = sum * (1.f / 128.f);
    mu[r] = m2;
    rstd[r] = rsqrtf(sq * (1.f / 128.f) - m2 * m2 + 1e-5f);
  }
  const int trow = qt * 64 + w * 16 + lq * 4;
#pragma unroll
  for (int cb = 0; cb < 8; cb++) {
    const int dcol = h * HD + cb * 16 + lm;
    const float g = gamma[dcol], be = beta[dcol];
#pragma unroll
    for (int r = 0; r < 4; r++) {
      float val = (o[cb][r] - mu[r]) * rstd[r] * g + be;
      yb[(size_t)(b * T_SEQ + trow + r) * D_MOD + dcol] = f2bf(val);
    }
  }
}

// ---------------------------------------------------------------------------
extern "C" void kernel_launch(void* const* d_in, const int* in_sizes, int n_in,
                              void* d_out, int out_size, void* d_ws,
                              size_t ws_size, hipStream_t stream) {
  const float* x     = (const float*)d_in[0];
  const float* Wq    = (const float*)d_in[1];
  const float* Wk    = (const float*)d_in[2];
  const float* Wv    = (const float*)d_in[3];
  const float* Wo    = (const float*)d_in[4];
  const float* bo    = (const float*)d_in[5];
  const float* theta = (const float*)d_in[6];
  const float* gamma = (const float*)d_in[7];
  const float* beta  = (const float*)d_in[8];
  float* out = (float*)d_out;

  char* ws = (char*)d_ws;
  const size_t MB = 1024 * 1024;
  short* qb = (short*)(ws + 0 * MB);    // 8 MB bf16 (B,H,T,HD)
  short* kb = (short*)(ws + 8 * MB);    // 8 MB
  short* vb = (short*)(ws + 16 * MB);   // 8 MB
  short* yb = (short*)(ws + 24 * MB);   // 8 MB bf16 (B*T, D)
  short* xb = (short*)(ws + 32 * MB);   // 8 MB bf16 (B*T, D)
  short* wt = (short*)(ws + 40 * MB);   // 8 MB: 4x (1024,1024) bf16 W^T
  float* dm = (float*)(ws + 48 * MB);   // 8 KB decay table

  decay_kernel<<<dim3(8), dim3(256), 0, stream>>>(theta, dm);
  cvt_x<<<dim3(2048), dim3(256), 0, stream>>>(x, xb);
  cvt_w<<<dim3(32, 32, 4), dim3(256), 0, stream>>>(Wq, Wk, Wv, Wo, wt);
  gemm_qkv<<<dim3(32, 8, 3), dim3(256), 0, stream>>>(xb, wt, qb, kb, vb);
  attn_kernel<<<dim3(512), dim3(256), 0, stream>>>(qb, kb, vb, dm, gamma, beta, yb);
  gemm_out<<<dim3(32, 8), dim3(256), 0, stream>>>(
      yb, wt + (size_t)3 * D_MOD * D_MOD, bo, out);
}

// Round 9
// 211.186 us; speedup vs baseline: 1.2656x; 1.0349x over previous
//
#include <hip/hip_runtime.h>

#define B_SZ  2
#define T_SEQ 2048
#define D_MOD 1024
#define NH    8
#define HD    128

typedef __attribute__((ext_vector_type(8))) short short8;   // 8 x bf16 frag
typedef __attribute__((ext_vector_type(4))) float f32x4;    // mfma accumulator

__device__ __forceinline__ short f2bf(float f) {
  unsigned u = __float_as_uint(f);
  unsigned r = u + 0x7fffu + ((u >> 16) & 1u);   // RNE
  return (short)(r >> 16);
}

__device__ __forceinline__ void gld_lds16(const short* g, short* l) {
  __builtin_amdgcn_global_load_lds(
      (const __attribute__((address_space(1))) void*)g,
      (__attribute__((address_space(3))) void*)l, 16, 0, 0);
}

// ---------------- decay table: dm[n] = mean_h exp(-theta_h*n) / sqrt(HD) ----
__global__ void decay_kernel(const float* __restrict__ theta,
                             float* __restrict__ dm) {
  int n = blockIdx.x * 256 + threadIdx.x;
  if (n >= T_SEQ) return;
  float nf = (float)n;
  float s = 0.f;
#pragma unroll
  for (int h = 0; h < NH; h++) s += __expf(-theta[h] * nf);
  dm[n] = s * (0.08838834764831845f / 8.0f);  // (1/sqrt(128)) * (1/H)
}

// ---------------- x fp32 -> bf16 (same layout) -----------------------------
__global__ __launch_bounds__(256) void cvt_x(const float* __restrict__ x,
                                             short* __restrict__ xb) {
  int i = (blockIdx.x * 256 + threadIdx.x) * 8;
  float4 a = *(const float4*)(x + i);
  float4 b = *(const float4*)(x + i + 4);
  short8 o;
  o[0] = f2bf(a.x); o[1] = f2bf(a.y); o[2] = f2bf(a.z); o[3] = f2bf(a.w);
  o[4] = f2bf(b.x); o[5] = f2bf(b.y); o[6] = f2bf(b.z); o[7] = f2bf(b.w);
  *(short8*)(xb + i) = o;
}

// ---------------- W (K,N) fp32 -> W^T (N,K) bf16, 32x32 LDS transpose ------
__global__ __launch_bounds__(256) void cvt_w(const float* __restrict__ Wq,
                                             const float* __restrict__ Wk,
                                             const float* __restrict__ Wv,
                                             const float* __restrict__ Wo,
                                             short* __restrict__ wt) {
  __shared__ float t[32][33];
  const int z = blockIdx.z;
  const float* __restrict__ W = (z == 0) ? Wq : (z == 1) ? Wk : (z == 2) ? Wv : Wo;
  short* __restrict__ dst = wt + (size_t)z * D_MOD * D_MOD;
  const int k0 = blockIdx.x * 32, n0 = blockIdx.y * 32;
  const int tx = threadIdx.x & 31, ty = threadIdx.x >> 5;
#pragma unroll
  for (int i = 0; i < 4; i++)
    t[ty * 4 + i][tx] = W[(size_t)(k0 + ty * 4 + i) * D_MOD + n0 + tx];
  __syncthreads();
#pragma unroll
  for (int i = 0; i < 4; i++)
    dst[(size_t)(n0 + ty * 4 + i) * D_MOD + k0 + tx] = f2bf(t[tx][ty * 4 + i]);
}

// ---------------- bf16 MFMA GEMM (m97 structure): QKV projections ----------
__global__ __launch_bounds__(256, 3) void gemm_qkv(
    const short* __restrict__ xb, const short* __restrict__ wt,
    short* __restrict__ qb, short* __restrict__ kb, short* __restrict__ vb) {
  __shared__ __align__(16) short As[128 * 32];   // [row][k] row-major, 8KB
  __shared__ __align__(16) short Bs[128 * 32];   // [col][k] (W^T rows), 8KB
  const int tid = threadIdx.x;
  const int l = tid & 63, w = tid >> 6;
  const int wr = w >> 1, wc = w & 1;
  const int row0 = blockIdx.x * 128;
  const int h = blockIdx.y;
  const int col0 = h * 128;
  const short* __restrict__ Wt = wt + (size_t)blockIdx.z * D_MOD * D_MOD;
  short* __restrict__ dst = (blockIdx.z == 0) ? qb : (blockIdx.z == 1) ? kb : vb;

  f32x4 acc[4][4];
#pragma unroll
  for (int m = 0; m < 4; m++)
#pragma unroll
    for (int n = 0; n < 4; n++) acc[m][n] = (f32x4){0.f, 0.f, 0.f, 0.f};

  const int cA = w * 2;
  const int sr = l >> 2;
  const int skq = (l & 3) << 3;

#pragma unroll
  for (int i = 0; i < 2; i++) {
    int c = cA + i;
    gld_lds16(xb + (size_t)(row0 + c * 16 + sr) * D_MOD + skq, As + c * 512);
    gld_lds16(Wt + (size_t)(col0 + c * 16 + sr) * D_MOD + skq, Bs + c * 512);
  }
  for (int ks = 0; ks < 32; ks++) {
    __syncthreads();
    short8 af[4], bf[4];
#pragma unroll
    for (int m = 0; m < 4; m++)
      af[m] = *(const short8*)&As[(wr * 64 + m * 16 + (l & 15)) * 32 + (l >> 4) * 8];
#pragma unroll
    for (int n = 0; n < 4; n++)
      bf[n] = *(const short8*)&Bs[(wc * 64 + n * 16 + (l & 15)) * 32 + (l >> 4) * 8];
#pragma unroll
    for (int m = 0; m < 4; m++)
#pragma unroll
      for (int n = 0; n < 4; n++)
        acc[m][n] =
            __builtin_amdgcn_mfma_f32_16x16x32_bf16(af[m], bf[n], acc[m][n], 0, 0, 0);
    __syncthreads();
    if (ks < 31) {
      const int k0 = (ks + 1) * 32;
#pragma unroll
      for (int i = 0; i < 2; i++) {
        int c = cA + i;
        gld_lds16(xb + (size_t)(row0 + c * 16 + sr) * D_MOD + k0 + skq, As + c * 512);
        gld_lds16(Wt + (size_t)(col0 + c * 16 + sr) * D_MOD + k0 + skq, Bs + c * 512);
      }
    }
  }
#pragma unroll
  for (int m = 0; m < 4; m++) {
#pragma unroll
    for (int j = 0; j < 4; j++) {
      int row = row0 + wr * 64 + m * 16 + (l >> 4) * 4 + j;
      int bb = row >> 11, t = row & (T_SEQ - 1);
      size_t base = ((size_t)(bb * NH + h) * T_SEQ + t) * HD + wc * 64 + (l & 15);
#pragma unroll
      for (int n = 0; n < 4; n++) dst[base + n * 16] = f2bf(acc[m][n][j]);
    }
  }
}

// ---------------- bf16 MFMA GEMM: output projection + bias (fp32 out) ------
__global__ __launch_bounds__(256, 3) void gemm_out(
    const short* __restrict__ yb, const short* __restrict__ wot,
    const float* __restrict__ bias, float* __restrict__ out) {
  __shared__ __align__(16) short As[128 * 32];
  __shared__ __align__(16) short Bs[128 * 32];
  const int tid = threadIdx.x;
  const int l = tid & 63, w = tid >> 6;
  const int wr = w >> 1, wc = w & 1;
  const int row0 = blockIdx.x * 128;
  const int col0 = blockIdx.y * 128;

  f32x4 acc[4][4];
#pragma unroll
  for (int m = 0; m < 4; m++)
#pragma unroll
    for (int n = 0; n < 4; n++) acc[m][n] = (f32x4){0.f, 0.f, 0.f, 0.f};

  const int cA = w * 2;
  const int sr = l >> 2;
  const int skq = (l & 3) << 3;

#pragma unroll
  for (int i = 0; i < 2; i++) {
    int c = cA + i;
    gld_lds16(yb + (size_t)(row0 + c * 16 + sr) * D_MOD + skq, As + c * 512);
    gld_lds16(wot + (size_t)(col0 + c * 16 + sr) * D_MOD + skq, Bs + c * 512);
  }
  for (int ks = 0; ks < 32; ks++) {
    __syncthreads();
    short8 af[4], bf[4];
#pragma unroll
    for (int m = 0; m < 4; m++)
      af[m] = *(const short8*)&As[(wr * 64 + m * 16 + (l & 15)) * 32 + (l >> 4) * 8];
#pragma unroll
    for (int n = 0; n < 4; n++)
      bf[n] = *(const short8*)&Bs[(wc * 64 + n * 16 + (l & 15)) * 32 + (l >> 4) * 8];
#pragma unroll
    for (int m = 0; m < 4; m++)
#pragma unroll
      for (int n = 0; n < 4; n++)
        acc[m][n] =
            __builtin_amdgcn_mfma_f32_16x16x32_bf16(af[m], bf[n], acc[m][n], 0, 0, 0);
    __syncthreads();
    if (ks < 31) {
      const int k0 = (ks + 1) * 32;
#pragma unroll
      for (int i = 0; i < 2; i++) {
        int c = cA + i;
        gld_lds16(yb + (size_t)(row0 + c * 16 + sr) * D_MOD + k0 + skq, As + c * 512);
        gld_lds16(wot + (size_t)(col0 + c * 16 + sr) * D_MOD + k0 + skq, Bs + c * 512);
      }
    }
  }
#pragma unroll
  for (int m = 0; m < 4; m++) {
#pragma unroll
    for (int j = 0; j < 4; j++) {
      int row = row0 + wr * 64 + m * 16 + (l >> 4) * 4 + j;
#pragma unroll
      for (int n = 0; n < 4; n++) {
        int col = col0 + wc * 64 + n * 16 + (l & 15);
        out[(size_t)row * D_MOD + col] = acc[m][n][j] + bias[col];
      }
    }
  }
}

// ---------------- flash retention, balanced complementary pairing ----------
// grid = 512 blocks (XCD-swizzled), 256 threads = 4 waves, 16 q-rows/wave.
// Triangular workload (qt+1 tiles/block). Co-resident blocks (pbid, pbid+256)
// map to lbid, lbid+32 -> complementary qt (sum=31): each CU gets ~33 tile-
// units instead of up to 64. Swapped QK^T, in-register softmax, dbuf K/V,
// descending j, defer-rescale, write-late V repack, one barrier/tile.
__global__ __launch_bounds__(256, 2) void attn_kernel(
    const short* __restrict__ qg, const short* __restrict__ kg,
    const short* __restrict__ vg, const float* __restrict__ dm_g,
    const float* __restrict__ gamma, const float* __restrict__ beta,
    short* __restrict__ yb) {
  __shared__ __align__(16) short KT[2][8192];   // 2 x 16KB [jb][kc][lane][8]
  __shared__ __align__(16) short VT[2][8192];   // 2 x 16KB [cb][kc2][lane][8]
  __shared__ float dm_s[T_SEQ];                 // 8KB decay table
  // total 72KB -> 2 blocks/CU

  const int tid = threadIdx.x;
  const int l = tid & 63, w = tid >> 6;
  const int lm = l & 15, lq = l >> 4;

  const unsigned pbid = blockIdx.x;
  const unsigned lbid = (pbid & 7) * 64 + (pbid >> 3);
  // complementary qt pairing: lbid and lbid+32 (likely co-resident under
  // round-robin dispatch) get qt summing to 31 -> balanced per-CU work.
  const int qraw = lbid & 31;
  const int qt = (lbid & 32) ? (31 - qraw) : qraw;
  const int h = (lbid >> 5) & 7;
  const int b = lbid >> 8;

  const size_t hoff = (size_t)(b * NH + h) * T_SEQ * HD;
  const short* __restrict__ Qh = qg + hoff;
  const short* __restrict__ Kh = kg + hoff;
  const short* __restrict__ Vh = vg + hoff;

  for (int i = tid * 4; i < T_SEQ; i += 1024)
    *(float4*)&dm_s[i] = *(const float4*)&dm_g[i];

  short8 qf[4];
  {
    int row = qt * 64 + w * 16 + lm;
#pragma unroll
    for (int kc = 0; kc < 4; kc++)
      qf[kc] = *(const short8*)(Qh + (size_t)row * HD + kc * 32 + lq * 8);
  }

  f32x4 zero4 = {0.f, 0.f, 0.f, 0.f};
  f32x4 o[8];
#pragma unroll
  for (int cb = 0; cb < 8; cb++) o[cb] = zero4;
  float m_r = -1e30f, l_r = 0.f;   // per-lane: q-row = lm of this wave

  const int i_row = qt * 64 + w * 16 + lm;   // softmax row owned by this lane
  const int d0 = l * 2;
  const int srcA = lm + 32 * (lq & 1);       // P-exchange source lanes
  const int srcB = srcA + 16;
  unsigned vv[16];

  // ---- prologue: stage tile t=qt into buffer 0
  {
    const int jP = qt * 64;
#pragma unroll
    for (int kc = 0; kc < 4; kc++)
      gld_lds16(Kh + (size_t)(jP + w * 16 + lm) * HD + kc * 32 + lq * 8,
                &KT[0][(w * 4 + kc) * 512]);
#pragma unroll
    for (int p = 0; p < 2; p++)
#pragma unroll
      for (int jj = 0; jj < 8; jj++)
        vv[p * 8 + jj] =
            *(const unsigned*)(Vh + (size_t)(jP + (w + p * 4) * 8 + jj) * HD + d0);
#pragma unroll
    for (int p = 0; p < 2; p++) {
      const int jl = (w + p * 4) * 8;
      const int kc2 = jl >> 5, bq = (jl >> 3) & 3;
#pragma unroll
      for (int dd = 0; dd < 2; dd++) {
        const int d = d0 + dd;
        short8 col;
#pragma unroll
        for (int jj = 0; jj < 8; jj++) {
          unsigned u = vv[p * 8 + jj];
          col[jj] = (short)(dd ? (u >> 16) : (u & 0xffffu));
        }
        *(short8*)&VT[0][(((d >> 4) * 2 + kc2) * 64 + bq * 16 + (d & 15)) * 8] = col;
      }
    }
  }
  __syncthreads();

  int cur = 0;
  for (int t = qt; t >= 0; --t) {
    const int j0 = t * 64;
    const int nxt = cur ^ 1;
    const bool pf = (t > 0);

    // ---- issue-early: prefetch tile t-1 (K -> LDS direct, V -> regs)
    if (pf) {
      const int jn = j0 - 64;
#pragma unroll
      for (int kc = 0; kc < 4; kc++)
        gld_lds16(Kh + (size_t)(jn + w * 16 + lm) * HD + kc * 32 + lq * 8,
                  &KT[nxt][(w * 4 + kc) * 512]);
#pragma unroll
      for (int p = 0; p < 2; p++)
#pragma unroll
        for (int jj = 0; jj < 8; jj++)
          vv[p * 8 + jj] =
              *(const unsigned*)(Vh + (size_t)(jn + (w + p * 4) * 8 + jj) * HD + d0);
    }

    // ---- register-block: ALL 16 K frags first (pipelined ds_read_b128)
    short8 kfr[16];
#pragma unroll
    for (int jb = 0; jb < 4; jb++)
#pragma unroll
      for (int kc = 0; kc < 4; kc++)
        kfr[jb * 4 + kc] = *(const short8*)&KT[cur][((jb * 4 + kc) * 64 + l) * 8];

    // ---- swapped QK^T: S^T[k][q], lane holds k = jb*16 + lq*4 + r, q = lm
    float s[4][4];
    __builtin_amdgcn_s_setprio(1);
#pragma unroll
    for (int jb = 0; jb < 4; jb++) {
      f32x4 acc = zero4;
#pragma unroll
      for (int kc = 0; kc < 4; kc++)
        acc = __builtin_amdgcn_mfma_f32_16x16x32_bf16(kfr[jb * 4 + kc], qf[kc],
                                                      acc, 0, 0, 0);
#pragma unroll
      for (int r = 0; r < 4; r++) {
        int delta = i_row - (j0 + jb * 16 + lq * 4 + r);
        float sv = acc[r] * dm_s[delta & (T_SEQ - 1)];
        s[jb][r] = (delta >= 0) ? sv : -__builtin_inff();
      }
    }
    __builtin_amdgcn_s_setprio(0);

    // ---- issue ALL 16 V frag reads now; latency hides under softmax
    short8 vfr[16];
#pragma unroll
    for (int cb = 0; cb < 8; cb++)
#pragma unroll
      for (int kc2 = 0; kc2 < 2; kc2++)
        vfr[cb * 2 + kc2] =
            *(const short8*)&VT[cur][((cb * 2 + kc2) * 64 + l) * 8];

    // ---- defer-rescale online softmax, fully in-register
    float lmax = fmaxf(fmaxf(fmaxf(s[0][0], s[0][1]), fmaxf(s[0][2], s[0][3])),
                       fmaxf(fmaxf(s[1][0], s[1][1]), fmaxf(s[1][2], s[1][3])));
    lmax = fmaxf(lmax,
                 fmaxf(fmaxf(fmaxf(s[2][0], s[2][1]), fmaxf(s[2][2], s[2][3])),
                       fmaxf(fmaxf(s[3][0], s[3][1]), fmaxf(s[3][2], s[3][3]))));
    if (__any(lmax > m_r + 4.0f)) {
      float mx = lmax;
      mx = fmaxf(mx, __shfl_xor(mx, 16));
      mx = fmaxf(mx, __shfl_xor(mx, 32));
      float mnew = fmaxf(m_r, mx);
      float fac = __expf(m_r - mnew);
      m_r = mnew;
      l_r *= fac;
      float facr[4];
#pragma unroll
      for (int r = 0; r < 4; r++) facr[r] = __shfl(fac, lq * 4 + r);
#pragma unroll
      for (int cb = 0; cb < 8; cb++)
#pragma unroll
        for (int r = 0; r < 4; r++) o[cb][r] *= facr[r];
    }

    float lsum = 0.f;
#pragma unroll
    for (int jb = 0; jb < 4; jb++)
#pragma unroll
      for (int r = 0; r < 4; r++) {
        float pv = __expf(s[jb][r] - m_r);
        s[jb][r] = pv;
        lsum += pv;
      }
    lsum += __shfl_xor(lsum, 16);
    lsum += __shfl_xor(lsum, 32);
    l_r += lsum;

    // ---- pack P to bf16 pairs, redistribute to A-frag via shfl
    unsigned pw[4][2];
#pragma unroll
    for (int jb = 0; jb < 4; jb++) {
      asm("v_cvt_pk_bf16_f32 %0, %1, %2"
          : "=v"(pw[jb][0]) : "v"(s[jb][0]), "v"(s[jb][1]));
      asm("v_cvt_pk_bf16_f32 %0, %1, %2"
          : "=v"(pw[jb][1]) : "v"(s[jb][2]), "v"(s[jb][3]));
    }

    __builtin_amdgcn_s_setprio(1);
#pragma unroll
    for (int kc2 = 0; kc2 < 2; kc2++) {
      unsigned w0a = __shfl((int)pw[2 * kc2][0], srcA);
      unsigned w0b = __shfl((int)pw[2 * kc2 + 1][0], srcA);
      unsigned w1a = __shfl((int)pw[2 * kc2][1], srcA);
      unsigned w1b = __shfl((int)pw[2 * kc2 + 1][1], srcA);
      unsigned w2a = __shfl((int)pw[2 * kc2][0], srcB);
      unsigned w2b = __shfl((int)pw[2 * kc2 + 1][0], srcB);
      unsigned w3a = __shfl((int)pw[2 * kc2][1], srcB);
      unsigned w3b = __shfl((int)pw[2 * kc2 + 1][1], srcB);
      const bool hi = (lq & 2) != 0;
      unsigned w0 = hi ? w0b : w0a;
      unsigned w1 = hi ? w1b : w1a;
      unsigned w2 = hi ? w2b : w2a;
      unsigned w3 = hi ? w3b : w3a;
      short8 pb;
      pb[0] = (short)(w0 & 0xffffu); pb[1] = (short)(w0 >> 16);
      pb[2] = (short)(w1 & 0xffffu); pb[3] = (short)(w1 >> 16);
      pb[4] = (short)(w2 & 0xffffu); pb[5] = (short)(w2 >> 16);
      pb[6] = (short)(w3 & 0xffffu); pb[7] = (short)(w3 >> 16);
#pragma unroll
      for (int cb = 0; cb < 8; cb++)
        o[cb] = __builtin_amdgcn_mfma_f32_16x16x32_bf16(pb, vfr[cb * 2 + kc2],
                                                        o[cb], 0, 0, 0);
    }
    __builtin_amdgcn_s_setprio(0);

    // ---- write-late: repack prefetched V into the other buffer
    if (pf) {
#pragma unroll
      for (int p = 0; p < 2; p++) {
        const int jl = (w + p * 4) * 8;
        const int kc2 = jl >> 5, bq = (jl >> 3) & 3;
#pragma unroll
        for (int dd = 0; dd < 2; dd++) {
          const int d = d0 + dd;
          short8 col;
#pragma unroll
          for (int jj = 0; jj < 8; jj++) {
            unsigned u = vv[p * 8 + jj];
            col[jj] = (short)(dd ? (u >> 16) : (u & 0xffffu));
          }
          *(short8*)&VT[nxt][(((d >> 4) * 2 + kc2) * 64 + bq * 16 + (d & 15)) * 8] =
              col;
        }
      }
    }
    __syncthreads();  // next tile fully staged; cur free for overwrite
    cur = nxt;
  }

  // ---- epilogue: 1/l (via shfl from row-owner lanes), GroupNorm, write ----
  float linv[4];
#pragma unroll
  for (int r = 0; r < 4; r++) linv[r] = 1.0f / __shfl(l_r, lq * 4 + r);
  float mu[4], rstd[4];
#pragma unroll
  for (int r = 0; r < 4; r++) {
    float sum = 0.f, sq = 0.f;
#pragma unroll
    for (int cb = 0; cb < 8; cb++) {
      float v2 = o[cb][r] * linv[r];
      o[cb][r] = v2;
      sum += v2;
      sq += v2 * v2;
    }
    sum += __shfl_xor(sum, 1); sum += __shfl_xor(sum, 2);
    sum += __shfl_xor(sum, 4); sum += __shfl_xor(sum, 8);
    sq += __shfl_xor(sq, 1); sq += __shfl_xor(sq, 2);
    sq += __shfl_xor(sq, 4); sq += __shfl_xor(sq, 8);
    float m2 = sum * (1.f / 128.f);
    mu[r] = m2;
    rstd[r] = rsqrtf(sq * (1.f / 128.f) - m2 * m2 + 1e-5f);
  }
  const int trow = qt * 64 + w * 16 + lq * 4;
#pragma unroll
  for (int cb = 0; cb < 8; cb++) {
    const int dcol = h * HD + cb * 16 + lm;
    const float g = gamma[dcol], be = beta[dcol];
#pragma unroll
    for (int r = 0; r < 4; r++) {
      float val = (o[cb][r] - mu[r]) * rstd[r] * g + be;
      yb[(size_t)(b * T_SEQ + trow + r) * D_MOD + dcol] = f2bf(val);
    }
  }
}

// ---------------------------------------------------------------------------
extern "C" void kernel_launch(void* const* d_in, const int* in_sizes, int n_in,
                              void* d_out, int out_size, void* d_ws,
                              size_t ws_size, hipStream_t stream) {
  const float* x     = (const float*)d_in[0];
  const float* Wq    = (const float*)d_in[1];
  const float* Wk    = (const float*)d_in[2];
  const float* Wv    = (const float*)d_in[3];
  const float* Wo    = (const float*)d_in[4];
  const float* bo    = (const float*)d_in[5];
  const float* theta = (const float*)d_in[6];
  const float* gamma = (const float*)d_in[7];
  const float* beta  = (const float*)d_in[8];
  float* out = (float*)d_out;

  char* ws = (char*)d_ws;
  const size_t MB = 1024 * 1024;
  short* qb = (short*)(ws + 0 * MB);    // 8 MB bf16 (B,H,T,HD)
  short* kb = (short*)(ws + 8 * MB);    // 8 MB
  short* vb = (short*)(ws + 16 * MB);   // 8 MB
  short* yb = (short*)(ws + 24 * MB);   // 8 MB bf16 (B*T, D)
  short* xb = (short*)(ws + 32 * MB);   // 8 MB bf16 (B*T, D)
  short* wt = (short*)(ws + 40 * MB);   // 8 MB: 4x (1024,1024) bf16 W^T
  float* dm = (float*)(ws + 48 * MB);   // 8 KB decay table

  decay_kernel<<<dim3(8), dim3(256), 0, stream>>>(theta, dm);
  cvt_x<<<dim3(2048), dim3(256), 0, stream>>>(x, xb);
  cvt_w<<<dim3(32, 32, 4), dim3(256), 0, stream>>>(Wq, Wk, Wv, Wo, wt);
  gemm_qkv<<<dim3(32, 8, 3), dim3(256), 0, stream>>>(xb, wt, qb, kb, vb);
  attn_kernel<<<dim3(512), dim3(256), 0, stream>>>(qb, kb, vb, dm, gamma, beta, yb);
  gemm_out<<<dim3(32, 8), dim3(256), 0, stream>>>(
      yb, wt + (size_t)3 * D_MOD * D_MOD, bo, out);
}